// Round 5
// baseline (4001.814 us; speedup 1.0000x reference)
//
#include <hip/hip_runtime.h>
#include <math.h>

// ---------------------------------------------------------------------------
// TemporalFusionTransformer forward, fp32 baseline (correctness anchor).
// B=512, F=9, H=128, L=2, NH=4, OUT=6, T_ENC=168, T_DEC=24.
// r5: comb-GRN fused into VSN tail -> ws = 45,877,248 floats = 183.5 MB.
// ---------------------------------------------------------------------------

#define DI __device__ __forceinline__

#define B_    512
#define TE    168
#define TDD   24
#define F_    9
#define H_    128
#define OUT_  6
#define CHUNK 56   // 168 = 3*56

DI float sigmoid_f(float x){ return 1.0f/(1.0f + __expf(-x)); }
DI float tanh_f(float x){
  float xc = fminf(fmaxf(x, -15.0f), 15.0f);
  float t = __expf(2.0f*xc);
  return (t - 1.0f) / (t + 1.0f);
}
DI float elu_f(float x){ return x > 0.0f ? x : (__expf(x) - 1.0f); }
DI float comp4(const float4 v, int u){ return u==0 ? v.x : (u==1 ? v.y : (u==2 ? v.z : v.w)); }

// ---------------------------------------------------------------------------
// Dual-B GEMM microkernel step: acc{A,B}[4][8] += Ht-tile @ Wt{A,B}-tile
// Ht: [64][132] LDS, Wt*: [32][132] LDS, 256 threads = (tr 0..15) x (tc 0..15)
// ---------------------------------------------------------------------------
DI void gemm_tile_2(const float* Ht, const float* WtA, const float* WtB,
                    float accA[4][8], float accB[4][8], int tr, int tc, int kt)
{
  #pragma unroll
  for (int k4 = 0; k4 < 8; ++k4){
    float4 a4[4];
    #pragma unroll
    for (int i = 0; i < 4; ++i)
      a4[i] = *(const float4*)&Ht[(tr*4+i)*132 + kt*32 + k4*4];
    #pragma unroll
    for (int u = 0; u < 4; ++u){
      float4 bAlo = *(const float4*)&WtA[(k4*4+u)*132 + tc*8];
      float4 bAhi = *(const float4*)&WtA[(k4*4+u)*132 + tc*8 + 4];
      float4 bBlo = *(const float4*)&WtB[(k4*4+u)*132 + tc*8];
      float4 bBhi = *(const float4*)&WtB[(k4*4+u)*132 + tc*8 + 4];
      #pragma unroll
      for (int i = 0; i < 4; ++i){
        float av = comp4(a4[i], u);
        #pragma unroll
        for (int j = 0; j < 8; ++j){
          float bA = (j < 4) ? comp4(bAlo, j) : comp4(bAhi, j-4);
          float bB = (j < 4) ? comp4(bBlo, j) : comp4(bBhi, j-4);
          accA[i][j] = fmaf(av, bA, accA[i][j]);
          accB[i][j] = fmaf(av, bB, accB[i][j]);
        }
      }
    }
  }
}

DI void gemm_tile_1(const float* Ht, const float* Wt, float acc[4][8],
                    int tr, int tc, int kt)
{
  #pragma unroll
  for (int k4 = 0; k4 < 8; ++k4){
    float4 a4[4];
    #pragma unroll
    for (int i = 0; i < 4; ++i)
      a4[i] = *(const float4*)&Ht[(tr*4+i)*132 + kt*32 + k4*4];
    #pragma unroll
    for (int u = 0; u < 4; ++u){
      float4 blo = *(const float4*)&Wt[(k4*4+u)*132 + tc*8];
      float4 bhi = *(const float4*)&Wt[(k4*4+u)*132 + tc*8 + 4];
      #pragma unroll
      for (int i = 0; i < 4; ++i){
        float av = comp4(a4[i], u);
        #pragma unroll
        for (int j = 0; j < 8; ++j){
          float bv = (j < 4) ? comp4(blo, j) : comp4(bhi, j-4);
          acc[i][j] = fmaf(av, bv, acc[i][j]);
        }
      }
    }
  }
}

// ---------------------------------------------------------------------------
// Kernel 1: fused VSN + complete comb-GRN.
// Per block: 64 (b,t) rows. For each feature f: build h1 in LDS, GEMM fc2 &
// gate, per-feature LayerNorm -> proc tile; accumulate proc@comb_fc1_w and
// proc@comb_skip_w into persistent register tiles (full 128-col rows).
// Tail (fused comb-GRN): Ht <- elu(Z1); GEMM with comb_fc2/comb_gate;
// val = S + h*sigmoid(g); LayerNorm -> combined. No Z1/S HBM round-trip.
// ---------------------------------------------------------------------------
__global__ __launch_bounds__(256, 2) void vsn_comb_kernel(
    const float* __restrict__ x,
    const float* __restrict__ w1,  const float* __restrict__ b1,
    const float* __restrict__ w2,  const float* __restrict__ b2,
    const float* __restrict__ wg,  const float* __restrict__ bg,
    const float* __restrict__ wsk, const float* __restrict__ bsk,
    const float* __restrict__ lns, const float* __restrict__ lnb,
    const float* __restrict__ cfc1w, const float* __restrict__ cfc1b,
    const float* __restrict__ cskw,  const float* __restrict__ cskb,
    const float* __restrict__ cfc2w, const float* __restrict__ cfc2b,
    const float* __restrict__ cgw,   const float* __restrict__ cgb,
    const float* __restrict__ clns,  const float* __restrict__ clnb,
    float* __restrict__ outp)
{
  __shared__ float Ht[64*132];
  __shared__ float WtA[32*132];
  __shared__ float WtB[32*132];
  __shared__ float xcol[64];
  __shared__ float vecs[8*128]; // w1,b1,b2,bg,wsk,bsk,lns,lnb rows for f

  const int tid = threadIdx.x;
  const int tr = tid >> 4, tc = tid & 15;
  const int row0 = blockIdx.x * 64;

  float acc1[4][8], accS[4][8];
  #pragma unroll
  for (int i = 0; i < 4; ++i)
    #pragma unroll
    for (int j = 0; j < 8; ++j){ acc1[i][j] = 0.f; accS[i][j] = 0.f; }

  for (int f = 0; f < F_; ++f){
    __syncthreads(); // protect LDS from previous iteration readers
    if (tid < 64){
      int r = row0 + tid;
      int b = r / TE, t = r - b*TE;
      xcol[tid] = x[((long)b*192 + t)*F_ + f];
    } else if (tid >= 128){
      int c = tid - 128;
      vecs[0*128+c] = w1 [f*128+c];
      vecs[1*128+c] = b1 [f*128+c];
      vecs[2*128+c] = b2 [f*128+c];
      vecs[3*128+c] = bg [f*128+c];
      vecs[4*128+c] = wsk[f*128+c];
      vecs[5*128+c] = bsk[f*128+c];
      vecs[6*128+c] = lns[f*128+c];
      vecs[7*128+c] = lnb[f*128+c];
    }
    __syncthreads();
    // h1 = elu(x*w1 + b1) into Ht
    #pragma unroll
    for (int i = 0; i < 8; ++i){
      int fi = tid + i*256;
      int row = fi >> 5, c4 = (fi & 31)*4;
      float xv = xcol[row];
      float4 wv = *(const float4*)&vecs[0*128 + c4];
      float4 bv = *(const float4*)&vecs[1*128 + c4];
      float4 hv;
      hv.x = elu_f(fmaf(xv, wv.x, bv.x));
      hv.y = elu_f(fmaf(xv, wv.y, bv.y));
      hv.z = elu_f(fmaf(xv, wv.z, bv.z));
      hv.w = elu_f(fmaf(xv, wv.w, bv.w));
      *(float4*)&Ht[row*132 + c4] = hv;
    }

    // GEMM h1@fc2_w[f], h1@gate_w[f]
    float T2[4][8], Gg[4][8];
    #pragma unroll
    for (int i = 0; i < 4; ++i)
      #pragma unroll
      for (int j = 0; j < 8; ++j){ T2[i][j] = 0.f; Gg[i][j] = 0.f; }

    const float* W2f = w2 + f*16384;
    const float* Wgf = wg + f*16384;
    for (int kt = 0; kt < 4; ++kt){
      __syncthreads();
      #pragma unroll
      for (int i = 0; i < 4; ++i){
        int li = tid + i*256;
        int kk = li >> 5, c4 = (li & 31)*4;
        *(float4*)&WtA[kk*132 + c4] = *(const float4*)&W2f[(kt*32+kk)*128 + c4];
        *(float4*)&WtB[kk*132 + c4] = *(const float4*)&Wgf[(kt*32+kk)*128 + c4];
      }
      __syncthreads();
      gemm_tile_2(Ht, WtA, WtB, T2, Gg, tr, tc, kt);
    }

    // epilogue: val = skip + h*g ; two-pass LN over 128 cols
    float val[4][8];
    #pragma unroll
    for (int i = 0; i < 4; ++i){
      float xv = xcol[tr*4 + i];
      #pragma unroll
      for (int j = 0; j < 8; ++j){
        int c = tc*8 + j;
        float hv = T2[i][j] + vecs[2*128+c];
        float gv = sigmoid_f(Gg[i][j] + vecs[3*128+c]);
        float sv = fmaf(xv, vecs[4*128+c], vecs[5*128+c]);
        val[i][j] = sv + hv*gv;
      }
    }
    #pragma unroll
    for (int i = 0; i < 4; ++i){
      float s = 0.f;
      #pragma unroll
      for (int j = 0; j < 8; ++j) s += val[i][j];
      #pragma unroll
      for (int m = 1; m < 16; m <<= 1) s += __shfl_xor(s, m, 64);
      float mu = s * (1.0f/128.0f);
      float vs = 0.f;
      #pragma unroll
      for (int j = 0; j < 8; ++j){ float d = val[i][j]-mu; vs += d*d; }
      #pragma unroll
      for (int m = 1; m < 16; m <<= 1) vs += __shfl_xor(vs, m, 64);
      float rstd = rsqrtf(vs * (1.0f/128.0f) + 1e-5f);
      #pragma unroll
      for (int j = 0; j < 8; ++j){
        int c = tc*8 + j;
        val[i][j] = (val[i][j]-mu)*rstd*vecs[6*128+c] + vecs[7*128+c];
      }
    }
    __syncthreads();  // all reads of Ht (h1) complete
    #pragma unroll
    for (int i = 0; i < 4; ++i)
      #pragma unroll
      for (int j = 0; j < 8; ++j)
        Ht[(tr*4+i)*132 + tc*8 + j] = val[i][j];   // proc tile

    // accumulate comb fc1 / skip with proc as A
    const float* W1f = cfc1w + f*16384;
    const float* Wsf = cskw  + f*16384;
    for (int kt = 0; kt < 4; ++kt){
      __syncthreads();
      #pragma unroll
      for (int i = 0; i < 4; ++i){
        int li = tid + i*256;
        int kk = li >> 5, c4 = (li & 31)*4;
        *(float4*)&WtA[kk*132 + c4] = *(const float4*)&W1f[(kt*32+kk)*128 + c4];
        *(float4*)&WtB[kk*132 + c4] = *(const float4*)&Wsf[(kt*32+kk)*128 + c4];
      }
      __syncthreads();
      gemm_tile_2(Ht, WtA, WtB, acc1, accS, tr, tc, kt);
    }
  }

  // ------------------- fused comb-GRN tail -------------------
  // acc1 = Z1 - cfc1b ; accS = S - cskb (full 128-col rows per block).
  __syncthreads();  // final gemm_tile_2 reads of Ht complete
  #pragma unroll
  for (int i = 0; i < 4; ++i)
    #pragma unroll
    for (int j = 0; j < 8; ++j){
      int c = tc*8 + j;
      Ht[(tr*4+i)*132 + c] = elu_f(acc1[i][j] + cfc1b[c]);
      accS[i][j] += cskb[c];
    }

  float T2[4][8], Gg[4][8];
  #pragma unroll
  for (int i = 0; i < 4; ++i)
    #pragma unroll
    for (int j = 0; j < 8; ++j){ T2[i][j] = 0.f; Gg[i][j] = 0.f; }

  for (int kt = 0; kt < 4; ++kt){
    __syncthreads();   // covers elu-Ht writes (kt=0) and WtA/WtB reuse (kt>0)
    #pragma unroll
    for (int i = 0; i < 4; ++i){
      int li = tid + i*256;
      int kk = li >> 5, c4 = (li & 31)*4;
      *(float4*)&WtA[kk*132 + c4] = *(const float4*)&cfc2w[(kt*32+kk)*128 + c4];
      *(float4*)&WtB[kk*132 + c4] = *(const float4*)&cgw  [(kt*32+kk)*128 + c4];
    }
    __syncthreads();
    gemm_tile_2(Ht, WtA, WtB, T2, Gg, tr, tc, kt);
  }

  float val[4][8];
  #pragma unroll
  for (int i = 0; i < 4; ++i)
    #pragma unroll
    for (int j = 0; j < 8; ++j){
      int c = tc*8 + j;
      float hv = (T2[i][j] + cfc2b[c]) * sigmoid_f(Gg[i][j] + cgb[c]);
      val[i][j] = accS[i][j] + hv;
    }
  #pragma unroll
  for (int i = 0; i < 4; ++i){
    float s = 0.f;
    #pragma unroll
    for (int j = 0; j < 8; ++j) s += val[i][j];
    #pragma unroll
    for (int m = 1; m < 16; m <<= 1) s += __shfl_xor(s, m, 64);
    float mu = s * (1.0f/128.0f);
    float vs = 0.f;
    #pragma unroll
    for (int j = 0; j < 8; ++j){ float d = val[i][j]-mu; vs += d*d; }
    #pragma unroll
    for (int m = 1; m < 16; m <<= 1) vs += __shfl_xor(vs, m, 64);
    float rstd = rsqrtf(vs * (1.0f/128.0f) + 1e-5f);
    long r = row0 + tr*4 + i;
    #pragma unroll
    for (int j = 0; j < 8; ++j){
      int c = tc*8 + j;
      outp[r*128 + c] = (val[i][j]-mu)*rstd*clns[c] + clnb[c];
    }
  }
}

// ---------------------------------------------------------------------------
// Kernel 2: GRN core (standalone; used for post-GRN, M=12288).
// out = LN(S + (elu(Z1)@fc2w + fc2b)*sigmoid(elu(Z1)@gw + gb))
// ---------------------------------------------------------------------------
__global__ __launch_bounds__(256, 2) void grn_core_kernel(
    const float* __restrict__ Z1, const float* __restrict__ S,
    const float* __restrict__ fc2w, const float* __restrict__ fc2b,
    const float* __restrict__ gw,   const float* __restrict__ gb,
    const float* __restrict__ lns,  const float* __restrict__ lnb,
    float* __restrict__ outp, int M)
{
  __shared__ float Ht[64*132];
  __shared__ float WtA[32*132];
  __shared__ float WtB[32*132];

  const int tid = threadIdx.x;
  const int tr = tid >> 4, tc = tid & 15;
  const int row0 = blockIdx.x * 64;

  #pragma unroll
  for (int i = 0; i < 8; ++i){
    int fi = tid + i*256;
    int row = fi >> 5, c4 = (fi & 31)*4;
    long r = row0 + row;
    float4 z = make_float4(0.f,0.f,0.f,0.f);
    if (r < M) z = *(const float4*)&Z1[r*128 + c4];
    z.x = elu_f(z.x); z.y = elu_f(z.y); z.z = elu_f(z.z); z.w = elu_f(z.w);
    *(float4*)&Ht[row*132 + c4] = z;
  }

  float T2[4][8], Gg[4][8];
  #pragma unroll
  for (int i = 0; i < 4; ++i)
    #pragma unroll
    for (int j = 0; j < 8; ++j){ T2[i][j] = 0.f; Gg[i][j] = 0.f; }

  for (int kt = 0; kt < 4; ++kt){
    __syncthreads();
    #pragma unroll
    for (int i = 0; i < 4; ++i){
      int li = tid + i*256;
      int kk = li >> 5, c4 = (li & 31)*4;
      *(float4*)&WtA[kk*132 + c4] = *(const float4*)&fc2w[(kt*32+kk)*128 + c4];
      *(float4*)&WtB[kk*132 + c4] = *(const float4*)&gw  [(kt*32+kk)*128 + c4];
    }
    __syncthreads();
    gemm_tile_2(Ht, WtA, WtB, T2, Gg, tr, tc, kt);
  }

  float val[4][8];
  #pragma unroll
  for (int i = 0; i < 4; ++i){
    long r = row0 + tr*4 + i;
    float4 s0 = make_float4(0,0,0,0), s1 = make_float4(0,0,0,0);
    if (r < M){
      s0 = *(const float4*)&S[r*128 + tc*8];
      s1 = *(const float4*)&S[r*128 + tc*8 + 4];
    }
    #pragma unroll
    for (int j = 0; j < 8; ++j){
      int c = tc*8 + j;
      float sv = (j < 4) ? comp4(s0, j) : comp4(s1, j-4);
      float hv = (T2[i][j] + fc2b[c]) * sigmoid_f(Gg[i][j] + gb[c]);
      val[i][j] = sv + hv;
    }
  }
  #pragma unroll
  for (int i = 0; i < 4; ++i){
    float s = 0.f;
    #pragma unroll
    for (int j = 0; j < 8; ++j) s += val[i][j];
    #pragma unroll
    for (int m = 1; m < 16; m <<= 1) s += __shfl_xor(s, m, 64);
    float mu = s * (1.0f/128.0f);
    float vs = 0.f;
    #pragma unroll
    for (int j = 0; j < 8; ++j){ float d = val[i][j]-mu; vs += d*d; }
    #pragma unroll
    for (int m = 1; m < 16; m <<= 1) vs += __shfl_xor(vs, m, 64);
    float rstd = rsqrtf(vs * (1.0f/128.0f) + 1e-5f);
    long r = row0 + tr*4 + i;
    if (r < M){
      #pragma unroll
      for (int j = 0; j < 8; ++j){
        int c = tc*8 + j;
        outp[r*128 + c] = (val[i][j]-mu)*rstd*lns[c] + lnb[c];
      }
    }
  }
}

// ---------------------------------------------------------------------------
// Kernel 3: generic tiled SGEMM, K=128 fixed. C[M,N] = A @ B + bias.
// A rows mapped as r -> A + (r/a_group)*a_group_stride + (r%a_group)*lda.
// wtrans=1: W is (N,128) row-major (y = x@W^T); wtrans=0: W is (128,128) direct.
// ---------------------------------------------------------------------------
__global__ __launch_bounds__(256, 2) void gemm_kernel(
    const float* __restrict__ A, const float* __restrict__ W,
    const float* __restrict__ bias, float* __restrict__ Cout,
    int M, int ldc, int a_group, long a_group_stride, int lda, int wtrans)
{
  __shared__ float Ht[64*132];
  __shared__ float Wt[32*132];

  const int tid = threadIdx.x;
  const int tr = tid >> 4, tc = tid & 15;
  const int row0 = blockIdx.x * 64;
  const int n0 = blockIdx.y * 128;

  #pragma unroll
  for (int i = 0; i < 8; ++i){
    int fi = tid + i*256;
    int row = fi >> 5, c4 = (fi & 31)*4;
    int r = row0 + row;
    float4 av = make_float4(0,0,0,0);
    if (r < M){
      int bg = r / a_group; int tt = r - bg*a_group;
      av = *(const float4*)&A[(long)bg*a_group_stride + (long)tt*lda + c4];
    }
    *(float4*)&Ht[row*132 + c4] = av;
  }

  float acc[4][8];
  #pragma unroll
  for (int i = 0; i < 4; ++i)
    #pragma unroll
    for (int j = 0; j < 8; ++j) acc[i][j] = 0.f;

  for (int kt = 0; kt < 4; ++kt){
    __syncthreads();
    if (wtrans){
      #pragma unroll
      for (int i = 0; i < 4; ++i){
        int li = tid + i*256;       // 0..1023
        int n = li >> 3, kq = (li & 7)*4;
        float4 wv = *(const float4*)&W[(long)(n0 + n)*128 + kt*32 + kq];
        Wt[(kq+0)*132 + n] = wv.x;
        Wt[(kq+1)*132 + n] = wv.y;
        Wt[(kq+2)*132 + n] = wv.z;
        Wt[(kq+3)*132 + n] = wv.w;
      }
    } else {
      #pragma unroll
      for (int i = 0; i < 4; ++i){
        int li = tid + i*256;
        int kk = li >> 5, c4 = (li & 31)*4;
        *(float4*)&Wt[kk*132 + c4] = *(const float4*)&W[(long)(kt*32+kk)*128 + n0 + c4];
      }
    }
    __syncthreads();
    gemm_tile_1(Ht, Wt, acc, tr, tc, kt);
  }

  float4 ba = *(const float4*)&bias[n0 + tc*8];
  float4 bb = *(const float4*)&bias[n0 + tc*8 + 4];
  #pragma unroll
  for (int i = 0; i < 4; ++i){
    long r = row0 + tr*4 + i;
    if (r < M){
      float4 o0, o1;
      o0.x = acc[i][0]+ba.x; o0.y = acc[i][1]+ba.y; o0.z = acc[i][2]+ba.z; o0.w = acc[i][3]+ba.w;
      o1.x = acc[i][4]+bb.x; o1.y = acc[i][5]+bb.y; o1.z = acc[i][6]+bb.z; o1.w = acc[i][7]+bb.w;
      *(float4*)&Cout[r*ldc + n0 + tc*8]     = o0;
      *(float4*)&Cout[r*ldc + n0 + tc*8 + 4] = o1;
    }
  }
}

// ---------------------------------------------------------------------------
// Kernel 4: LSTM recurrence. Batch-parallel: block owns 2 batch elements for
// all timesteps. Thread owns 1 gate row; Whh row persistent in VGPRs;
// h broadcast per step via v_readlane (VALU) to avoid LDS-read bound.
// ---------------------------------------------------------------------------
__global__ __launch_bounds__(512, 2) void lstm_rec_kernel(
    const float* __restrict__ gx, int nsteps, int gbs, int gts,
    const float* __restrict__ Whh,
    float* __restrict__ h_state, float* __restrict__ c_state, int init_zero,
    float* __restrict__ seq_out, long seq_b_stride)
{
  __shared__ float hbuf[2][128];
  __shared__ float act[4][2][128];

  const int tid = threadIdx.x;
  const int lane = tid & 63;
  const int b0 = blockIdx.x * 2;
  const int type = tid >> 7;
  const int u = tid & 127;

  float4 w[32];
  #pragma unroll
  for (int i = 0; i < 32; ++i)
    w[i] = *(const float4*)&Whh[(long)tid*128 + i*4];

  if (tid < 256){
    int bi = tid >> 7, uu = tid & 127;
    hbuf[bi][uu] = init_zero ? 0.f : h_state[(long)(b0+bi)*128 + uu];
  }
  float creg0 = 0.f, creg1 = 0.f;
  if (tid < 128 && !init_zero){
    creg0 = c_state[(long)b0*128 + tid];
    creg1 = c_state[(long)(b0+1)*128 + tid];
  }

  for (int t = 0; t < nsteps; ++t){
    __syncthreads();
    float hA0 = hbuf[0][lane],    hA1 = hbuf[0][64+lane];
    float hB0 = hbuf[1][lane],    hB1 = hbuf[1][64+lane];
    float acc0  = gx[(long)b0*gbs     + (long)t*gts + tid];
    float acc1  = gx[(long)(b0+1)*gbs + (long)t*gts + tid];
    float acc0b = 0.f, acc1b = 0.f;
    #pragma unroll
    for (int j = 0; j < 64; ++j){
      float wv = comp4(w[j>>2], j&3);
      float s0 = __int_as_float(__builtin_amdgcn_readlane(__float_as_int(hA0), j));
      float s1 = __int_as_float(__builtin_amdgcn_readlane(__float_as_int(hB0), j));
      acc0 = fmaf(wv, s0, acc0);
      acc1 = fmaf(wv, s1, acc1);
    }
    #pragma unroll
    for (int j = 0; j < 64; ++j){
      float wv = comp4(w[16 + (j>>2)], j&3);
      float s0 = __int_as_float(__builtin_amdgcn_readlane(__float_as_int(hA1), j));
      float s1 = __int_as_float(__builtin_amdgcn_readlane(__float_as_int(hB1), j));
      acc0b = fmaf(wv, s0, acc0b);
      acc1b = fmaf(wv, s1, acc1b);
    }
    acc0 += acc0b; acc1 += acc1b;

    float a0, a1;
    if (type == 2){ a0 = tanh_f(acc0); a1 = tanh_f(acc1); }
    else          { a0 = sigmoid_f(acc0); a1 = sigmoid_f(acc1); }
    act[type][0][u] = a0;
    act[type][1][u] = a1;
    __syncthreads();
    if (tid < 128){
      float cn0 = act[1][0][u]*creg0 + act[0][0][u]*act[2][0][u];
      float hn0 = act[3][0][u]*tanh_f(cn0);
      creg0 = cn0;
      float cn1 = act[1][1][u]*creg1 + act[0][1][u]*act[2][1][u];
      float hn1 = act[3][1][u]*tanh_f(cn1);
      creg1 = cn1;
      hbuf[0][u] = hn0;
      hbuf[1][u] = hn1;
      seq_out[(long)b0*seq_b_stride     + (long)t*128 + u] = hn0;
      seq_out[(long)(b0+1)*seq_b_stride + (long)t*128 + u] = hn1;
    }
  }
  __syncthreads();
  if (tid < 256){
    int bi = tid >> 7, uu = tid & 127;
    h_state[(long)(b0+bi)*128 + uu] = hbuf[bi][uu];
  }
  if (tid < 128){
    c_state[(long)b0*128 + tid]     = creg0;
    c_state[(long)(b0+1)*128 + tid] = creg1;
  }
}

// ---------------------------------------------------------------------------
// Kernel 5: attention core per (batch, head): scores + softmax + ctx.
// ---------------------------------------------------------------------------
__global__ __launch_bounds__(256) void attn_kernel(
    const float* __restrict__ q, const float* __restrict__ k,
    const float* __restrict__ v, float* __restrict__ ctx)
{
  __shared__ float kb[168*33];
  __shared__ float vbuf[168*33];
  __shared__ float qb[24*33];
  __shared__ float sc[24*172];

  const int tid = threadIdx.x;
  const int bh = blockIdx.x;
  const int b = bh >> 2, h = bh & 3;

  for (int l = tid; l < 1344; l += 256){
    int t = l >> 3, d4 = (l & 7)*4;
    float4 kv = *(const float4*)&k[((long)(b*168 + t))*128 + h*32 + d4];
    kb[t*33+d4+0] = kv.x; kb[t*33+d4+1] = kv.y; kb[t*33+d4+2] = kv.z; kb[t*33+d4+3] = kv.w;
    float4 vv = *(const float4*)&v[((long)(b*168 + t))*128 + h*32 + d4];
    vbuf[t*33+d4+0] = vv.x; vbuf[t*33+d4+1] = vv.y; vbuf[t*33+d4+2] = vv.z; vbuf[t*33+d4+3] = vv.w;
  }
  if (tid < 192){
    int t = tid >> 3, d4 = (tid & 7)*4;
    float4 qv = *(const float4*)&q[((long)(b*24 + t))*128 + h*32 + d4];
    qb[t*33+d4+0] = qv.x; qb[t*33+d4+1] = qv.y; qb[t*33+d4+2] = qv.z; qb[t*33+d4+3] = qv.w;
  }
  __syncthreads();

  if (tid < 168){
    int j = tid;
    for (int i = 0; i < 24; ++i){
      float s = 0.f;
      #pragma unroll
      for (int d = 0; d < 32; ++d)
        s = fmaf(qb[i*33+d], kb[j*33+d], s);
      sc[i*172 + j] = s * 0.17677669529663687f;  // 1/sqrt(32)
    }
  }
  __syncthreads();

  const int lane = tid & 63;
  const int wv = tid >> 6;
  for (int m = 0; m < 6; ++m){
    int i = wv + 4*m;
    float v0 = sc[i*172 + lane];
    float v1 = sc[i*172 + 64 + lane];
    float v2 = (lane < 40) ? sc[i*172 + 128 + lane] : -1e30f;
    float mx = fmaxf(v0, fmaxf(v1, v2));
    #pragma unroll
    for (int s = 1; s < 64; s <<= 1) mx = fmaxf(mx, __shfl_xor(mx, s, 64));
    float e0 = __expf(v0 - mx), e1 = __expf(v1 - mx);
    float e2 = (lane < 40) ? __expf(v2 - mx) : 0.f;
    float sm = e0 + e1 + e2;
    #pragma unroll
    for (int s = 1; s < 64; s <<= 1) sm += __shfl_xor(sm, s, 64);
    float inv = 1.0f / sm;
    sc[i*172 + lane]      = e0*inv;
    sc[i*172 + 64 + lane] = e1*inv;
    if (lane < 40) sc[i*172 + 128 + lane] = e2*inv;
  }
  __syncthreads();

  #pragma unroll
  for (int kk = 0; kk < 3; ++kk){
    int o = tid + kk*256;    // 0..767
    int i = o >> 5, d = o & 31;
    float s = 0.f;
    for (int j = 0; j < 168; ++j)
      s = fmaf(sc[i*172 + j], vbuf[j*33 + d], s);
    ctx[((long)(b*24 + i))*128 + h*32 + d] = s;
  }
}

// ---------------------------------------------------------------------------
// Kernel 6: final projection out = post @ fc_out_w + fc_out_b, (12288,128)->(12288,6)
// ---------------------------------------------------------------------------
__global__ void fcout_kernel(const float* __restrict__ post,
                             const float* __restrict__ w,
                             const float* __restrict__ bias,
                             float* __restrict__ out)
{
  int gid = blockIdx.x*256 + threadIdx.x;
  if (gid >= 12288*OUT_) return;
  int r = gid / OUT_, o = gid - r*OUT_;
  float s = bias[o];
  #pragma unroll 8
  for (int kk = 0; kk < 128; ++kk)
    s = fmaf(post[(long)r*128 + kk], w[kk*OUT_ + o], s);
  out[gid] = s;
}

// Kernel 7: bias sums (bih+bhh) for all 4 LSTM layers.
__global__ void biasprep_kernel(const float* __restrict__ ebih, const float* __restrict__ ebhh,
                                const float* __restrict__ dbih, const float* __restrict__ dbhh,
                                float* __restrict__ outb)
{
  int i = blockIdx.x*256 + threadIdx.x;
  if (i < 1024)       outb[i] = ebih[i] + ebhh[i];
  else if (i < 2048)  outb[i] = dbih[i-1024] + dbhh[i-1024];
}

// ---------------------------------------------------------------------------
extern "C" void kernel_launch(void* const* d_in, const int* in_sizes, int n_in,
                              void* d_out, int out_size, void* d_ws, size_t ws_size,
                              hipStream_t stream)
{
  const float* x_g   = (const float*)d_in[0];
  const float* vfc1w = (const float*)d_in[1];
  const float* vfc1b = (const float*)d_in[2];
  const float* vfc2w = (const float*)d_in[3];
  const float* vfc2b = (const float*)d_in[4];
  const float* vgw   = (const float*)d_in[5];
  const float* vgb   = (const float*)d_in[6];
  const float* vskw  = (const float*)d_in[7];
  const float* vskb  = (const float*)d_in[8];
  const float* vlns  = (const float*)d_in[9];
  const float* vlnb  = (const float*)d_in[10];
  const float* cfc1w = (const float*)d_in[11];
  const float* cfc1b = (const float*)d_in[12];
  const float* cfc2w = (const float*)d_in[13];
  const float* cfc2b = (const float*)d_in[14];
  const float* cgw   = (const float*)d_in[15];
  const float* cgb   = (const float*)d_in[16];
  const float* cskw  = (const float*)d_in[17];
  const float* cskb  = (const float*)d_in[18];
  const float* clns  = (const float*)d_in[19];
  const float* clnb  = (const float*)d_in[20];
  const float* eWih  = (const float*)d_in[21];
  const float* eWhh  = (const float*)d_in[22];
  const float* ebih  = (const float*)d_in[23];
  const float* ebhh  = (const float*)d_in[24];
  const float* dWih  = (const float*)d_in[25];
  const float* dWhh  = (const float*)d_in[26];
  const float* dbih  = (const float*)d_in[27];
  const float* dbhh  = (const float*)d_in[28];
  const float* qkvw  = (const float*)d_in[29];
  const float* qkvb  = (const float*)d_in[30];
  const float* aow   = (const float*)d_in[31];
  const float* aob   = (const float*)d_in[32];
  const float* pfc1w = (const float*)d_in[33];
  const float* pfc1b = (const float*)d_in[34];
  const float* pfc2w = (const float*)d_in[35];
  const float* pfc2b = (const float*)d_in[36];
  const float* pgw   = (const float*)d_in[37];
  const float* pgb   = (const float*)d_in[38];
  const float* plns  = (const float*)d_in[39];
  const float* plnb  = (const float*)d_in[40];
  const float* fcw   = (const float*)d_in[41];
  const float* fcb   = (const float*)d_in[42];
  // d_in[43]=encoder_steps(168), d_in[44]=forecast_steps(24): hardcoded.

  float* ws = (float*)d_ws;
  // workspace layout (floats); total 45,877,248 = 183.5 MB
  // R1: combined, then enc_out (combined dead after encoder L0)
  // R2: seq1, then decoder chain (seq1 dead after encoder L1)
  // D : gx chunks (14.68M max), then q/k/v (23.6M)
  float* R1 = ws;                       // 11,010,048
  float* R2 = ws + 11010048;            // 11,010,048
  float* Dd = ws + 22020096;            // 23,592,960
  float* st = ws + 45613056;            // states + biases (264,192)

  float* combined = R1;
  float* enc_out  = R1;
  float* seq1     = R2;
  float* dseq1    = R2;
  float* dec_out  = R2 + 1572864;
  float* ctxb     = R2 + 3145728;
  float* attn_o   = R2 + 4718592;
  float* z1p      = R2 + 6291456;
  float* postb    = R2 + 7864320;
  float* gxb      = Dd;
  float* qb       = Dd;
  float* kb       = Dd + 1572864;
  float* vb       = Dd + 12582912;
  float* h0s = st, *c0s = st + 65536, *h1s = st + 131072, *c1s = st + 196608;
  float* biasb = st + 262144;          // 4*512

  biasprep_kernel<<<8, 256, 0, stream>>>(ebih, ebhh, dbih, dbhh, biasb);

  // fused VSN + comb-GRN: writes `combined` directly (no Z1/S round-trip)
  vsn_comb_kernel<<<1344, 256, 0, stream>>>(x_g, vfc1w, vfc1b, vfc2w, vfc2b,
                                            vgw, vgb, vskw, vskb, vlns, vlnb,
                                            cfc1w, cfc1b, cskw, cskb,
                                            cfc2w, cfc2b, cgw, cgb, clns, clnb,
                                            combined);

  // encoder: 2 layers x 3 time-chunks of 56
  for (int l = 0; l < 2; ++l){
    const float* Wih = eWih + l*65536;
    const float* Whh = eWhh + l*65536;
    const float* src = (l == 0) ? combined : seq1;
    float* dst = (l == 0) ? seq1 : enc_out;    // L1 overwrites R1 (combined dead)
    float* hs  = (l == 0) ? h0s : h1s;
    float* cs  = (l == 0) ? c0s : c1s;
    for (int c = 0; c < 3; ++c){
      int t0 = c*CHUNK;
      gemm_kernel<<<dim3(448,4), 256, 0, stream>>>(src + (long)t0*128, Wih,
          biasb + l*512, gxb, B_*CHUNK, 512, CHUNK, (long)TE*128, 128, 1);
      lstm_rec_kernel<<<256, 512, 0, stream>>>(gxb, CHUNK, CHUNK*512, 512, Whh,
          hs, cs, (c == 0) ? 1 : 0, dst + (long)t0*128, (long)TE*128);
    }
  }

  // decoder layer 1: input = enc_out[:,167,:] repeated (gx time-stride 0)
  gemm_kernel<<<dim3(8,4), 256, 0, stream>>>(enc_out + (long)167*128, dWih,
      biasb + 1024, gxb, B_, 512, 1, (long)TE*128, 128, 1);
  lstm_rec_kernel<<<256, 512, 0, stream>>>(gxb, TDD, 512, 0, dWhh,
      h0s, c0s, 0, dseq1, (long)TDD*128);

  // decoder layer 2
  gemm_kernel<<<dim3(192,4), 256, 0, stream>>>(dseq1, dWih + 65536,
      biasb + 1536, gxb, B_*TDD, 512, B_*TDD, 0, 128, 1);
  lstm_rec_kernel<<<256, 512, 0, stream>>>(gxb, TDD, TDD*512, 512, dWhh + 65536,
      h1s, c1s, 0, dec_out, (long)TDD*128);

  // attention projections
  gemm_kernel<<<dim3(192,1),  256, 0, stream>>>(dec_out, qkvw,        qkvb,     qb, B_*TDD, 128, B_*TDD, 0, 128, 1);
  gemm_kernel<<<dim3(1344,1), 256, 0, stream>>>(enc_out, qkvw+16384,  qkvb+128, kb, B_*TE,  128, B_*TE,  0, 128, 1);
  gemm_kernel<<<dim3(1344,1), 256, 0, stream>>>(enc_out, qkvw+32768,  qkvb+256, vb, B_*TE,  128, B_*TE,  0, 128, 1);

  attn_kernel<<<2048, 256, 0, stream>>>(qb, kb, vb, ctxb);

  gemm_kernel<<<dim3(192,1), 256, 0, stream>>>(ctxb,   aow,   aob,   attn_o, B_*TDD, 128, B_*TDD, 0, 128, 1);
  gemm_kernel<<<dim3(192,1), 256, 0, stream>>>(attn_o, pfc1w, pfc1b, z1p,    B_*TDD, 128, B_*TDD, 0, 128, 0);

  grn_core_kernel<<<192, 256, 0, stream>>>(z1p, attn_o, pfc2w, pfc2b, pgw, pgb,
                                           plns, plnb, postb, B_*TDD);

  fcout_kernel<<<288, 256, 0, stream>>>(postb, fcw, fcb, (float*)d_out);
}

// Round 6
// 2618.488 us; speedup vs baseline: 1.5283x; 1.5283x over previous
//
#include <hip/hip_runtime.h>
#include <math.h>

// ---------------------------------------------------------------------------
// TemporalFusionTransformer forward. r6: vsn_comb rewritten on MFMA
// (bf16 3-way split = fp32-equivalent precision, 6 mfma per K-chunk).
// B=512, F=9, H=128, L=2, NH=4, OUT=6, T_ENC=168, T_DEC=24.
// ws = 45,877,248 floats = 183.5 MB (packed weights live inside gx region).
// ---------------------------------------------------------------------------

#define DI __device__ __forceinline__

#define B_    512
#define TE    168
#define TDD   24
#define F_    9
#define H_    128
#define OUT_  6
#define CHUNK 56   // 168 = 3*56

typedef __attribute__((ext_vector_type(8))) short bf16x8;
typedef __attribute__((ext_vector_type(4))) float f32x4;

DI float sigmoid_f(float x){ return 1.0f/(1.0f + __expf(-x)); }
DI float tanh_f(float x){
  float xc = fminf(fmaxf(x, -15.0f), 15.0f);
  float t = __expf(2.0f*xc);
  return (t - 1.0f) / (t + 1.0f);
}
DI float elu_f(float x){ return x > 0.0f ? x : (__expf(x) - 1.0f); }
DI float comp4(const float4 v, int u){ return u==0 ? v.x : (u==1 ? v.y : (u==2 ? v.z : v.w)); }

// bf16 RNE conversion + exact 3-way split (hi+mid+lo covers full fp32 mantissa)
DI unsigned short f2bf(float f){
  unsigned u = __float_as_uint(f);
  unsigned r = (u + 0x7fffu + ((u >> 16) & 1u)) >> 16;
  return (unsigned short)r;
}
DI float bf2f(unsigned short h){ return __uint_as_float(((unsigned)h) << 16); }
DI void split3(float v, short& h, short& m, short& l){
  unsigned short a = f2bf(v);
  float r1 = v - bf2f(a);          // exact (Sterbenz-style)
  unsigned short b = f2bf(r1);
  float r2 = r1 - bf2f(b);         // exact
  h = (short)a; m = (short)b; l = (short)f2bf(r2);
}

// ---------------------------------------------------------------------------
// Weight pre-pack: 38 matrices (w2[9], wg[9], cfc1w[9], cskw[9], cfc2w, cgw),
// each 128x128 K-major, into MFMA B-fragment order [kc(4)][n(8)][lane(64)][j(8)]
// as three bf16 planes (hi/mid/lo).
// B-frag mapping: lane supplies col=n*16+(lane&15), k=kc*32+(lane>>4)*8+j.
// ---------------------------------------------------------------------------
__global__ void pack_kernel(const float* __restrict__ w2, const float* __restrict__ wg,
                            const float* __restrict__ cfc1w, const float* __restrict__ cskw,
                            const float* __restrict__ cfc2w, const float* __restrict__ cgw,
                            unsigned short* __restrict__ hiP,
                            unsigned short* __restrict__ miP,
                            unsigned short* __restrict__ loP)
{
  int o = blockIdx.x*256 + threadIdx.x;          // 38*16384 = 622592 total
  if (o >= 38*16384) return;
  int m = o >> 14;
  int r = o & 16383;
  int kc   = r >> 12;
  int n    = (r >> 9) & 7;
  int lane = (r >> 3) & 63;
  int j    = r & 7;
  int k = kc*32 + ((lane >> 4) << 3) + j;
  int c = n*16 + (lane & 15);
  const float* src;
  if      (m < 9)   src = w2    + m*16384;
  else if (m < 18)  src = wg    + (m-9)*16384;
  else if (m < 27)  src = cfc1w + (m-18)*16384;
  else if (m < 36)  src = cskw  + (m-27)*16384;
  else if (m == 36) src = cfc2w;
  else              src = cgw;
  float v = src[k*128 + c];
  short h, mm, l; split3(v, h, mm, l);
  hiP[o] = (unsigned short)h;
  miP[o] = (unsigned short)mm;
  loP[o] = (unsigned short)l;
}

// stage one matrix's 3 planes for one kc (3 x 8KB) into LDS, 256 threads
DI void stage3(const unsigned short* __restrict__ hiP,
               const unsigned short* __restrict__ miP,
               const unsigned short* __restrict__ loP,
               int mat, int kc, unsigned short* Bs, int tid)
{
  long off = (long)mat*16384 + kc*4096;
  const unsigned short* s0 = hiP + off;
  const unsigned short* s1 = miP + off;
  const unsigned short* s2 = loP + off;
  *(uint4*)&Bs[0*4096 + tid*8]        = *(const uint4*)&s0[tid*8];
  *(uint4*)&Bs[0*4096 + 2048 + tid*8] = *(const uint4*)&s0[2048 + tid*8];
  *(uint4*)&Bs[1*4096 + tid*8]        = *(const uint4*)&s1[tid*8];
  *(uint4*)&Bs[1*4096 + 2048 + tid*8] = *(const uint4*)&s1[2048 + tid*8];
  *(uint4*)&Bs[2*4096 + tid*8]        = *(const uint4*)&s2[tid*8];
  *(uint4*)&Bs[2*4096 + 2048 + tid*8] = *(const uint4*)&s2[2048 + tid*8];
}

// 6-mfma split-product accumulate over 8 column tiles for one kc
DI void gemm6(const unsigned short* Bs, bf16x8 aH, bf16x8 aM, bf16x8 aL,
              f32x4 acc[8], int lane)
{
  #pragma unroll
  for (int n = 0; n < 8; ++n){
    bf16x8 bH = *(const bf16x8*)&Bs[0*4096 + n*512 + lane*8];
    bf16x8 bM = *(const bf16x8*)&Bs[1*4096 + n*512 + lane*8];
    bf16x8 bL = *(const bf16x8*)&Bs[2*4096 + n*512 + lane*8];
    acc[n] = __builtin_amdgcn_mfma_f32_16x16x32_bf16(aH, bH, acc[n], 0,0,0);
    acc[n] = __builtin_amdgcn_mfma_f32_16x16x32_bf16(aH, bM, acc[n], 0,0,0);
    acc[n] = __builtin_amdgcn_mfma_f32_16x16x32_bf16(aM, bH, acc[n], 0,0,0);
    acc[n] = __builtin_amdgcn_mfma_f32_16x16x32_bf16(aM, bM, acc[n], 0,0,0);
    acc[n] = __builtin_amdgcn_mfma_f32_16x16x32_bf16(aH, bL, acc[n], 0,0,0);
    acc[n] = __builtin_amdgcn_mfma_f32_16x16x32_bf16(aL, bH, acc[n], 0,0,0);
  }
}

// ---------------------------------------------------------------------------
// Kernel 1 (MFMA): fused VSN + complete comb-GRN.
// Block = 64 rows x 128 cols; 4 waves, wave w owns rows [w*16, w*16+16).
// A-frag: lane row = lane&15, k = kc*32+(lane>>4)*8+j.
// C-frag: row = (lane>>4)*4+reg, col = n*16+(lane&15)  [verified layout].
// Ht rows are wave-private -> no cross-wave Ht hazards; barriers guard Bs only.
// ---------------------------------------------------------------------------
__global__ __launch_bounds__(256, 2) void vsn_comb_mfma(
    const float* __restrict__ x,
    const float* __restrict__ w1,  const float* __restrict__ b1,
    const float* __restrict__ b2,  const float* __restrict__ bg,
    const float* __restrict__ wsk, const float* __restrict__ bsk,
    const float* __restrict__ lns, const float* __restrict__ lnb,
    const float* __restrict__ cfc1b, const float* __restrict__ cskb,
    const float* __restrict__ cfc2b, const float* __restrict__ cgb,
    const float* __restrict__ clns,  const float* __restrict__ clnb,
    const unsigned short* __restrict__ hiP,
    const unsigned short* __restrict__ miP,
    const unsigned short* __restrict__ loP,
    float* __restrict__ outp)
{
  __shared__ __align__(16) float Ht[64*132];            // 33.8 KB
  __shared__ __align__(16) unsigned short Bs[3*4096];   // 24 KB
  __shared__ float vecs[8*128];                         // 4 KB
  __shared__ float xcol[64];

  const int tid  = threadIdx.x;
  const int wave = tid >> 6;
  const int lane = tid & 63;
  const int g16  = lane >> 4;
  const int l16  = lane & 15;
  const int arow = wave*16 + l16;       // block-local A row
  const int row0 = blockIdx.x * 64;

  const f32x4 z4 = {0.f, 0.f, 0.f, 0.f};
  f32x4 acc1[8], accS[8];
  #pragma unroll
  for (int n = 0; n < 8; ++n){ acc1[n] = z4; accS[n] = z4; }

  for (int f = 0; f < F_; ++f){
    __syncthreads();                    // xcol/vecs free
    if (tid < 64){
      int r = row0 + tid;
      int b = r / TE, t = r - b*TE;
      xcol[tid] = x[((long)b*192 + t)*F_ + f];
    } else if (tid >= 128){
      int c = tid - 128;
      vecs[0*128+c] = w1 [f*128+c];
      vecs[1*128+c] = b1 [f*128+c];
      vecs[2*128+c] = b2 [f*128+c];
      vecs[3*128+c] = bg [f*128+c];
      vecs[4*128+c] = wsk[f*128+c];
      vecs[5*128+c] = bsk[f*128+c];
      vecs[6*128+c] = lns[f*128+c];
      vecs[7*128+c] = lnb[f*128+c];
    }
    __syncthreads();

    f32x4 T2[8], Gg[8];
    #pragma unroll
    for (int n = 0; n < 8; ++n){ T2[n] = z4; Gg[n] = z4; }

    // ---- phase 1: T2,Gg = h1 @ (w2[f], wg[f]) ----
    for (int kc = 0; kc < 4; ++kc){
      __syncthreads();                  // Bs free
      stage3(hiP, miP, loP, f, kc, Bs, tid);       // w2[f]
      // build h1 A-frags in-register (no transpose needed)
      float xv = xcol[arow];
      int k0 = kc*32 + (g16 << 3);
      bf16x8 aH, aM, aL;
      #pragma unroll
      for (int j = 0; j < 8; ++j){
        float h = elu_f(fmaf(xv, vecs[0*128 + k0 + j], vecs[1*128 + k0 + j]));
        short sh, sm, sl; split3(h, sh, sm, sl);
        aH[j] = sh; aM[j] = sm; aL[j] = sl;
      }
      __syncthreads();                  // Bs staged
      gemm6(Bs, aH, aM, aL, T2, lane);
      __syncthreads();                  // Bs reads done
      stage3(hiP, miP, loP, 9+f, kc, Bs, tid);     // wg[f]
      __syncthreads();
      gemm6(Bs, aH, aM, aL, Gg, lane);
    }

    // ---- epilogue 1: val = skip + h*sig(g); per-feature LN -> proc -> Ht ----
    #pragma unroll
    for (int n = 0; n < 8; ++n){
      int c = n*16 + l16;
      float b2c = vecs[2*128+c], bgc = vecs[3*128+c];
      float wkc = vecs[4*128+c], bkc = vecs[5*128+c];
      #pragma unroll
      for (int r = 0; r < 4; ++r){
        float xv = xcol[wave*16 + (g16 << 2) + r];
        float hv = T2[n][r] + b2c;
        float gv = sigmoid_f(Gg[n][r] + bgc);
        T2[n][r] = fmaf(xv, wkc, bkc) + hv*gv;
      }
    }
    #pragma unroll
    for (int r = 0; r < 4; ++r){
      float s = 0.f;
      #pragma unroll
      for (int n = 0; n < 8; ++n) s += T2[n][r];
      #pragma unroll
      for (int m = 1; m < 16; m <<= 1) s += __shfl_xor(s, m, 64);
      float mu = s * (1.0f/128.0f);
      float vs = 0.f;
      #pragma unroll
      for (int n = 0; n < 8; ++n){ float d = T2[n][r]-mu; vs += d*d; }
      #pragma unroll
      for (int m = 1; m < 16; m <<= 1) vs += __shfl_xor(vs, m, 64);
      float rstd = rsqrtf(vs * (1.0f/128.0f) + 1e-5f);
      #pragma unroll
      for (int n = 0; n < 8; ++n){
        int c = n*16 + l16;
        T2[n][r] = (T2[n][r]-mu)*rstd*vecs[6*128+c] + vecs[7*128+c];
      }
    }
    #pragma unroll
    for (int n = 0; n < 8; ++n)
      #pragma unroll
      for (int r = 0; r < 4; ++r)
        Ht[(wave*16 + (g16<<2) + r)*132 + n*16 + l16] = T2[n][r];   // wave-private

    // ---- phase 2: acc1 += proc@cfc1w[f]; accS += proc@cskw[f] ----
    for (int kc = 0; kc < 4; ++kc){
      __syncthreads();
      stage3(hiP, miP, loP, 18+f, kc, Bs, tid);    // cfc1w[f]
      bf16x8 aH, aM, aL;
      {
        const float* hp = &Ht[arow*132 + kc*32 + (g16 << 3)];
        float4 v0 = *(const float4*)hp;
        float4 v1 = *(const float4*)(hp + 4);
        #pragma unroll
        for (int j = 0; j < 8; ++j){
          float v = (j < 4) ? comp4(v0, j) : comp4(v1, j-4);
          short sh, sm, sl; split3(v, sh, sm, sl);
          aH[j] = sh; aM[j] = sm; aL[j] = sl;
        }
      }
      __syncthreads();
      gemm6(Bs, aH, aM, aL, acc1, lane);
      __syncthreads();
      stage3(hiP, miP, loP, 27+f, kc, Bs, tid);    // cskw[f]
      __syncthreads();
      gemm6(Bs, aH, aM, aL, accS, lane);
    }
  }

  // ---- fused comb-GRN tail ----
  #pragma unroll
  for (int n = 0; n < 8; ++n){
    int c = n*16 + l16;
    float b1c = cfc1b[c], skc = cskb[c];
    #pragma unroll
    for (int r = 0; r < 4; ++r){
      Ht[(wave*16 + (g16<<2) + r)*132 + c] = elu_f(acc1[n][r] + b1c);
      accS[n][r] += skc;
    }
  }
  f32x4 T2[8], Gg[8];
  #pragma unroll
  for (int n = 0; n < 8; ++n){ T2[n] = z4; Gg[n] = z4; }

  for (int kc = 0; kc < 4; ++kc){
    __syncthreads();
    stage3(hiP, miP, loP, 36, kc, Bs, tid);        // cfc2w
    bf16x8 aH, aM, aL;
    {
      const float* hp = &Ht[arow*132 + kc*32 + (g16 << 3)];
      float4 v0 = *(const float4*)hp;
      float4 v1 = *(const float4*)(hp + 4);
      #pragma unroll
      for (int j = 0; j < 8; ++j){
        float v = (j < 4) ? comp4(v0, j) : comp4(v1, j-4);
        short sh, sm, sl; split3(v, sh, sm, sl);
        aH[j] = sh; aM[j] = sm; aL[j] = sl;
      }
    }
    __syncthreads();
    gemm6(Bs, aH, aM, aL, T2, lane);
    __syncthreads();
    stage3(hiP, miP, loP, 37, kc, Bs, tid);        // cgw
    __syncthreads();
    gemm6(Bs, aH, aM, aL, Gg, lane);
  }

  #pragma unroll
  for (int n = 0; n < 8; ++n){
    int c = n*16 + l16;
    float f2b = cfc2b[c], gbb = cgb[c];
    #pragma unroll
    for (int r = 0; r < 4; ++r){
      float hv = (T2[n][r] + f2b) * sigmoid_f(Gg[n][r] + gbb);
      T2[n][r] = accS[n][r] + hv;
    }
  }
  #pragma unroll
  for (int r = 0; r < 4; ++r){
    float s = 0.f;
    #pragma unroll
    for (int n = 0; n < 8; ++n) s += T2[n][r];
    #pragma unroll
    for (int m = 1; m < 16; m <<= 1) s += __shfl_xor(s, m, 64);
    float mu = s * (1.0f/128.0f);
    float vs = 0.f;
    #pragma unroll
    for (int n = 0; n < 8; ++n){ float d = T2[n][r]-mu; vs += d*d; }
    #pragma unroll
    for (int m = 1; m < 16; m <<= 1) vs += __shfl_xor(vs, m, 64);
    float rstd = rsqrtf(vs * (1.0f/128.0f) + 1e-5f);
    long rr = row0 + wave*16 + (g16<<2) + r;
    #pragma unroll
    for (int n = 0; n < 8; ++n){
      int c = n*16 + l16;
      outp[rr*128 + c] = (T2[n][r]-mu)*rstd*clns[c] + clnb[c];
    }
  }
}

// ---------------------------------------------------------------------------
// fp32 GEMM microkernel (kept for remaining kernels)
// ---------------------------------------------------------------------------
DI void gemm_tile_2(const float* Ht, const float* WtA, const float* WtB,
                    float accA[4][8], float accB[4][8], int tr, int tc, int kt)
{
  #pragma unroll
  for (int k4 = 0; k4 < 8; ++k4){
    float4 a4[4];
    #pragma unroll
    for (int i = 0; i < 4; ++i)
      a4[i] = *(const float4*)&Ht[(tr*4+i)*132 + kt*32 + k4*4];
    #pragma unroll
    for (int u = 0; u < 4; ++u){
      float4 bAlo = *(const float4*)&WtA[(k4*4+u)*132 + tc*8];
      float4 bAhi = *(const float4*)&WtA[(k4*4+u)*132 + tc*8 + 4];
      float4 bBlo = *(const float4*)&WtB[(k4*4+u)*132 + tc*8];
      float4 bBhi = *(const float4*)&WtB[(k4*4+u)*132 + tc*8 + 4];
      #pragma unroll
      for (int i = 0; i < 4; ++i){
        float av = comp4(a4[i], u);
        #pragma unroll
        for (int j = 0; j < 8; ++j){
          float bA = (j < 4) ? comp4(bAlo, j) : comp4(bAhi, j-4);
          float bB = (j < 4) ? comp4(bBlo, j) : comp4(bBhi, j-4);
          accA[i][j] = fmaf(av, bA, accA[i][j]);
          accB[i][j] = fmaf(av, bB, accB[i][j]);
        }
      }
    }
  }
}

DI void gemm_tile_1(const float* Ht, const float* Wt, float acc[4][8],
                    int tr, int tc, int kt)
{
  #pragma unroll
  for (int k4 = 0; k4 < 8; ++k4){
    float4 a4[4];
    #pragma unroll
    for (int i = 0; i < 4; ++i)
      a4[i] = *(const float4*)&Ht[(tr*4+i)*132 + kt*32 + k4*4];
    #pragma unroll
    for (int u = 0; u < 4; ++u){
      float4 blo = *(const float4*)&Wt[(k4*4+u)*132 + tc*8];
      float4 bhi = *(const float4*)&Wt[(k4*4+u)*132 + tc*8 + 4];
      #pragma unroll
      for (int i = 0; i < 4; ++i){
        float av = comp4(a4[i], u);
        #pragma unroll
        for (int j = 0; j < 8; ++j){
          float bv = (j < 4) ? comp4(blo, j) : comp4(bhi, j-4);
          acc[i][j] = fmaf(av, bv, acc[i][j]);
        }
      }
    }
  }
}

// ---------------------------------------------------------------------------
// Kernel 2: GRN core (post-GRN, M=12288)
// ---------------------------------------------------------------------------
__global__ __launch_bounds__(256, 2) void grn_core_kernel(
    const float* __restrict__ Z1, const float* __restrict__ S,
    const float* __restrict__ fc2w, const float* __restrict__ fc2b,
    const float* __restrict__ gw,   const float* __restrict__ gb,
    const float* __restrict__ lns,  const float* __restrict__ lnb,
    float* __restrict__ outp, int M)
{
  __shared__ float Ht[64*132];
  __shared__ float WtA[32*132];
  __shared__ float WtB[32*132];

  const int tid = threadIdx.x;
  const int tr = tid >> 4, tc = tid & 15;
  const int row0 = blockIdx.x * 64;

  #pragma unroll
  for (int i = 0; i < 8; ++i){
    int fi = tid + i*256;
    int row = fi >> 5, c4 = (fi & 31)*4;
    long r = row0 + row;
    float4 z = make_float4(0.f,0.f,0.f,0.f);
    if (r < M) z = *(const float4*)&Z1[r*128 + c4];
    z.x = elu_f(z.x); z.y = elu_f(z.y); z.z = elu_f(z.z); z.w = elu_f(z.w);
    *(float4*)&Ht[row*132 + c4] = z;
  }

  float T2[4][8], Gg[4][8];
  #pragma unroll
  for (int i = 0; i < 4; ++i)
    #pragma unroll
    for (int j = 0; j < 8; ++j){ T2[i][j] = 0.f; Gg[i][j] = 0.f; }

  for (int kt = 0; kt < 4; ++kt){
    __syncthreads();
    #pragma unroll
    for (int i = 0; i < 4; ++i){
      int li = tid + i*256;
      int kk = li >> 5, c4 = (li & 31)*4;
      *(float4*)&WtA[kk*132 + c4] = *(const float4*)&fc2w[(kt*32+kk)*128 + c4];
      *(float4*)&WtB[kk*132 + c4] = *(const float4*)&gw  [(kt*32+kk)*128 + c4];
    }
    __syncthreads();
    gemm_tile_2(Ht, WtA, WtB, T2, Gg, tr, tc, kt);
  }

  float val[4][8];
  #pragma unroll
  for (int i = 0; i < 4; ++i){
    long r = row0 + tr*4 + i;
    float4 s0 = make_float4(0,0,0,0), s1 = make_float4(0,0,0,0);
    if (r < M){
      s0 = *(const float4*)&S[r*128 + tc*8];
      s1 = *(const float4*)&S[r*128 + tc*8 + 4];
    }
    #pragma unroll
    for (int j = 0; j < 8; ++j){
      int c = tc*8 + j;
      float sv = (j < 4) ? comp4(s0, j) : comp4(s1, j-4);
      float hv = (T2[i][j] + fc2b[c]) * sigmoid_f(Gg[i][j] + gb[c]);
      val[i][j] = sv + hv;
    }
  }
  #pragma unroll
  for (int i = 0; i < 4; ++i){
    float s = 0.f;
    #pragma unroll
    for (int j = 0; j < 8; ++j) s += val[i][j];
    #pragma unroll
    for (int m = 1; m < 16; m <<= 1) s += __shfl_xor(s, m, 64);
    float mu = s * (1.0f/128.0f);
    float vs = 0.f;
    #pragma unroll
    for (int j = 0; j < 8; ++j){ float d = val[i][j]-mu; vs += d*d; }
    #pragma unroll
    for (int m = 1; m < 16; m <<= 1) vs += __shfl_xor(vs, m, 64);
    float rstd = rsqrtf(vs * (1.0f/128.0f) + 1e-5f);
    long r = row0 + tr*4 + i;
    if (r < M){
      #pragma unroll
      for (int j = 0; j < 8; ++j){
        int c = tc*8 + j;
        outp[r*128 + c] = (val[i][j]-mu)*rstd*lns[c] + lnb[c];
      }
    }
  }
}

// ---------------------------------------------------------------------------
// Kernel 3: generic tiled SGEMM, K=128 fixed.
// ---------------------------------------------------------------------------
__global__ __launch_bounds__(256, 2) void gemm_kernel(
    const float* __restrict__ A, const float* __restrict__ W,
    const float* __restrict__ bias, float* __restrict__ Cout,
    int M, int ldc, int a_group, long a_group_stride, int lda, int wtrans)
{
  __shared__ float Ht[64*132];
  __shared__ float Wt[32*132];

  const int tid = threadIdx.x;
  const int tr = tid >> 4, tc = tid & 15;
  const int row0 = blockIdx.x * 64;
  const int n0 = blockIdx.y * 128;

  #pragma unroll
  for (int i = 0; i < 8; ++i){
    int fi = tid + i*256;
    int row = fi >> 5, c4 = (fi & 31)*4;
    int r = row0 + row;
    float4 av = make_float4(0,0,0,0);
    if (r < M){
      int bg = r / a_group; int tt = r - bg*a_group;
      av = *(const float4*)&A[(long)bg*a_group_stride + (long)tt*lda + c4];
    }
    *(float4*)&Ht[row*132 + c4] = av;
  }

  float acc[4][8];
  #pragma unroll
  for (int i = 0; i < 4; ++i)
    #pragma unroll
    for (int j = 0; j < 8; ++j) acc[i][j] = 0.f;

  for (int kt = 0; kt < 4; ++kt){
    __syncthreads();
    if (wtrans){
      #pragma unroll
      for (int i = 0; i < 4; ++i){
        int li = tid + i*256;
        int n = li >> 3, kq = (li & 7)*4;
        float4 wv = *(const float4*)&W[(long)(n0 + n)*128 + kt*32 + kq];
        Wt[(kq+0)*132 + n] = wv.x;
        Wt[(kq+1)*132 + n] = wv.y;
        Wt[(kq+2)*132 + n] = wv.z;
        Wt[(kq+3)*132 + n] = wv.w;
      }
    } else {
      #pragma unroll
      for (int i = 0; i < 4; ++i){
        int li = tid + i*256;
        int kk = li >> 5, c4 = (li & 31)*4;
        *(float4*)&Wt[kk*132 + c4] = *(const float4*)&W[(long)(kt*32+kk)*128 + n0 + c4];
      }
    }
    __syncthreads();
    gemm_tile_1(Ht, Wt, acc, tr, tc, kt);
  }

  float4 ba = *(const float4*)&bias[n0 + tc*8];
  float4 bb = *(const float4*)&bias[n0 + tc*8 + 4];
  #pragma unroll
  for (int i = 0; i < 4; ++i){
    long r = row0 + tr*4 + i;
    if (r < M){
      float4 o0, o1;
      o0.x = acc[i][0]+ba.x; o0.y = acc[i][1]+ba.y; o0.z = acc[i][2]+ba.z; o0.w = acc[i][3]+ba.w;
      o1.x = acc[i][4]+bb.x; o1.y = acc[i][5]+bb.y; o1.z = acc[i][6]+bb.z; o1.w = acc[i][7]+bb.w;
      *(float4*)&Cout[r*ldc + n0 + tc*8]     = o0;
      *(float4*)&Cout[r*ldc + n0 + tc*8 + 4] = o1;
    }
  }
}

// ---------------------------------------------------------------------------
// Kernel 4: LSTM recurrence (batch-parallel, Whh in VGPRs, readlane broadcast)
// ---------------------------------------------------------------------------
__global__ __launch_bounds__(512, 2) void lstm_rec_kernel(
    const float* __restrict__ gx, int nsteps, int gbs, int gts,
    const float* __restrict__ Whh,
    float* __restrict__ h_state, float* __restrict__ c_state, int init_zero,
    float* __restrict__ seq_out, long seq_b_stride)
{
  __shared__ float hbuf[2][128];
  __shared__ float act[4][2][128];

  const int tid = threadIdx.x;
  const int lane = tid & 63;
  const int b0 = blockIdx.x * 2;
  const int type = tid >> 7;
  const int u = tid & 127;

  float4 w[32];
  #pragma unroll
  for (int i = 0; i < 32; ++i)
    w[i] = *(const float4*)&Whh[(long)tid*128 + i*4];

  if (tid < 256){
    int bi = tid >> 7, uu = tid & 127;
    hbuf[bi][uu] = init_zero ? 0.f : h_state[(long)(b0+bi)*128 + uu];
  }
  float creg0 = 0.f, creg1 = 0.f;
  if (tid < 128 && !init_zero){
    creg0 = c_state[(long)b0*128 + tid];
    creg1 = c_state[(long)(b0+1)*128 + tid];
  }

  for (int t = 0; t < nsteps; ++t){
    __syncthreads();
    float hA0 = hbuf[0][lane],    hA1 = hbuf[0][64+lane];
    float hB0 = hbuf[1][lane],    hB1 = hbuf[1][64+lane];
    float acc0  = gx[(long)b0*gbs     + (long)t*gts + tid];
    float acc1  = gx[(long)(b0+1)*gbs + (long)t*gts + tid];
    float acc0b = 0.f, acc1b = 0.f;
    #pragma unroll
    for (int j = 0; j < 64; ++j){
      float wv = comp4(w[j>>2], j&3);
      float s0 = __int_as_float(__builtin_amdgcn_readlane(__float_as_int(hA0), j));
      float s1 = __int_as_float(__builtin_amdgcn_readlane(__float_as_int(hB0), j));
      acc0 = fmaf(wv, s0, acc0);
      acc1 = fmaf(wv, s1, acc1);
    }
    #pragma unroll
    for (int j = 0; j < 64; ++j){
      float wv = comp4(w[16 + (j>>2)], j&3);
      float s0 = __int_as_float(__builtin_amdgcn_readlane(__float_as_int(hA1), j));
      float s1 = __int_as_float(__builtin_amdgcn_readlane(__float_as_int(hB1), j));
      acc0b = fmaf(wv, s0, acc0b);
      acc1b = fmaf(wv, s1, acc1b);
    }
    acc0 += acc0b; acc1 += acc1b;

    float a0, a1;
    if (type == 2){ a0 = tanh_f(acc0); a1 = tanh_f(acc1); }
    else          { a0 = sigmoid_f(acc0); a1 = sigmoid_f(acc1); }
    act[type][0][u] = a0;
    act[type][1][u] = a1;
    __syncthreads();
    if (tid < 128){
      float cn0 = act[1][0][u]*creg0 + act[0][0][u]*act[2][0][u];
      float hn0 = act[3][0][u]*tanh_f(cn0);
      creg0 = cn0;
      float cn1 = act[1][1][u]*creg1 + act[0][1][u]*act[2][1][u];
      float hn1 = act[3][1][u]*tanh_f(cn1);
      creg1 = cn1;
      hbuf[0][u] = hn0;
      hbuf[1][u] = hn1;
      seq_out[(long)b0*seq_b_stride     + (long)t*128 + u] = hn0;
      seq_out[(long)(b0+1)*seq_b_stride + (long)t*128 + u] = hn1;
    }
  }
  __syncthreads();
  if (tid < 256){
    int bi = tid >> 7, uu = tid & 127;
    h_state[(long)(b0+bi)*128 + uu] = hbuf[bi][uu];
  }
  if (tid < 128){
    c_state[(long)b0*128 + tid]     = creg0;
    c_state[(long)(b0+1)*128 + tid] = creg1;
  }
}

// ---------------------------------------------------------------------------
// Kernel 5: attention core per (batch, head)
// ---------------------------------------------------------------------------
__global__ __launch_bounds__(256) void attn_kernel(
    const float* __restrict__ q, const float* __restrict__ k,
    const float* __restrict__ v, float* __restrict__ ctx)
{
  __shared__ float kb[168*33];
  __shared__ float vbuf[168*33];
  __shared__ float qb[24*33];
  __shared__ float sc[24*172];

  const int tid = threadIdx.x;
  const int bh = blockIdx.x;
  const int b = bh >> 2, h = bh & 3;

  for (int l = tid; l < 1344; l += 256){
    int t = l >> 3, d4 = (l & 7)*4;
    float4 kv = *(const float4*)&k[((long)(b*168 + t))*128 + h*32 + d4];
    kb[t*33+d4+0] = kv.x; kb[t*33+d4+1] = kv.y; kb[t*33+d4+2] = kv.z; kb[t*33+d4+3] = kv.w;
    float4 vv = *(const float4*)&v[((long)(b*168 + t))*128 + h*32 + d4];
    vbuf[t*33+d4+0] = vv.x; vbuf[t*33+d4+1] = vv.y; vbuf[t*33+d4+2] = vv.z; vbuf[t*33+d4+3] = vv.w;
  }
  if (tid < 192){
    int t = tid >> 3, d4 = (tid & 7)*4;
    float4 qv = *(const float4*)&q[((long)(b*24 + t))*128 + h*32 + d4];
    qb[t*33+d4+0] = qv.x; qb[t*33+d4+1] = qv.y; qb[t*33+d4+2] = qv.z; qb[t*33+d4+3] = qv.w;
  }
  __syncthreads();

  if (tid < 168){
    int j = tid;
    for (int i = 0; i < 24; ++i){
      float s = 0.f;
      #pragma unroll
      for (int d = 0; d < 32; ++d)
        s = fmaf(qb[i*33+d], kb[j*33+d], s);
      sc[i*172 + j] = s * 0.17677669529663687f;
    }
  }
  __syncthreads();

  const int lane = tid & 63;
  const int wv = tid >> 6;
  for (int m = 0; m < 6; ++m){
    int i = wv + 4*m;
    float v0 = sc[i*172 + lane];
    float v1 = sc[i*172 + 64 + lane];
    float v2 = (lane < 40) ? sc[i*172 + 128 + lane] : -1e30f;
    float mx = fmaxf(v0, fmaxf(v1, v2));
    #pragma unroll
    for (int s = 1; s < 64; s <<= 1) mx = fmaxf(mx, __shfl_xor(mx, s, 64));
    float e0 = __expf(v0 - mx), e1 = __expf(v1 - mx);
    float e2 = (lane < 40) ? __expf(v2 - mx) : 0.f;
    float sm = e0 + e1 + e2;
    #pragma unroll
    for (int s = 1; s < 64; s <<= 1) sm += __shfl_xor(sm, s, 64);
    float inv = 1.0f / sm;
    sc[i*172 + lane]      = e0*inv;
    sc[i*172 + 64 + lane] = e1*inv;
    if (lane < 40) sc[i*172 + 128 + lane] = e2*inv;
  }
  __syncthreads();

  #pragma unroll
  for (int kk = 0; kk < 3; ++kk){
    int o = tid + kk*256;
    int i = o >> 5, d = o & 31;
    float s = 0.f;
    for (int j = 0; j < 168; ++j)
      s = fmaf(sc[i*172 + j], vbuf[j*33 + d], s);
    ctx[((long)(b*24 + i))*128 + h*32 + d] = s;
  }
}

// ---------------------------------------------------------------------------
// Kernel 6: final projection (12288,128)->(12288,6)
// ---------------------------------------------------------------------------
__global__ void fcout_kernel(const float* __restrict__ post,
                             const float* __restrict__ w,
                             const float* __restrict__ bias,
                             float* __restrict__ out)
{
  int gid = blockIdx.x*256 + threadIdx.x;
  if (gid >= 12288*OUT_) return;
  int r = gid / OUT_, o = gid - r*OUT_;
  float s = bias[o];
  #pragma unroll 8
  for (int kk = 0; kk < 128; ++kk)
    s = fmaf(post[(long)r*128 + kk], w[kk*OUT_ + o], s);
  out[gid] = s;
}

// Kernel 7: bias sums
__global__ void biasprep_kernel(const float* __restrict__ ebih, const float* __restrict__ ebhh,
                                const float* __restrict__ dbih, const float* __restrict__ dbhh,
                                float* __restrict__ outb)
{
  int i = blockIdx.x*256 + threadIdx.x;
  if (i < 1024)       outb[i] = ebih[i] + ebhh[i];
  else if (i < 2048)  outb[i] = dbih[i-1024] + dbhh[i-1024];
}

// ---------------------------------------------------------------------------
extern "C" void kernel_launch(void* const* d_in, const int* in_sizes, int n_in,
                              void* d_out, int out_size, void* d_ws, size_t ws_size,
                              hipStream_t stream)
{
  const float* x_g   = (const float*)d_in[0];
  const float* vfc1w = (const float*)d_in[1];
  const float* vfc1b = (const float*)d_in[2];
  const float* vfc2w = (const float*)d_in[3];
  const float* vfc2b = (const float*)d_in[4];
  const float* vgw   = (const float*)d_in[5];
  const float* vgb   = (const float*)d_in[6];
  const float* vskw  = (const float*)d_in[7];
  const float* vskb  = (const float*)d_in[8];
  const float* vlns  = (const float*)d_in[9];
  const float* vlnb  = (const float*)d_in[10];
  const float* cfc1w = (const float*)d_in[11];
  const float* cfc1b = (const float*)d_in[12];
  const float* cfc2w = (const float*)d_in[13];
  const float* cfc2b = (const float*)d_in[14];
  const float* cgw   = (const float*)d_in[15];
  const float* cgb   = (const float*)d_in[16];
  const float* cskw  = (const float*)d_in[17];
  const float* cskb  = (const float*)d_in[18];
  const float* clns  = (const float*)d_in[19];
  const float* clnb  = (const float*)d_in[20];
  const float* eWih  = (const float*)d_in[21];
  const float* eWhh  = (const float*)d_in[22];
  const float* ebih  = (const float*)d_in[23];
  const float* ebhh  = (const float*)d_in[24];
  const float* dWih  = (const float*)d_in[25];
  const float* dWhh  = (const float*)d_in[26];
  const float* dbih  = (const float*)d_in[27];
  const float* dbhh  = (const float*)d_in[28];
  const float* qkvw  = (const float*)d_in[29];
  const float* qkvb  = (const float*)d_in[30];
  const float* aow   = (const float*)d_in[31];
  const float* aob   = (const float*)d_in[32];
  const float* pfc1w = (const float*)d_in[33];
  const float* pfc1b = (const float*)d_in[34];
  const float* pfc2w = (const float*)d_in[35];
  const float* pfc2b = (const float*)d_in[36];
  const float* pgw   = (const float*)d_in[37];
  const float* pgb   = (const float*)d_in[38];
  const float* plns  = (const float*)d_in[39];
  const float* plnb  = (const float*)d_in[40];
  const float* fcw   = (const float*)d_in[41];
  const float* fcb   = (const float*)d_in[42];

  float* ws = (float*)d_ws;
  // total 45,877,248 floats = 183.5 MB (unchanged from r5)
  float* R1 = ws;                       // 11,010,048
  float* R2 = ws + 11010048;            // 11,010,048
  float* Dd = ws + 22020096;            // 23,592,960
  float* st = ws + 45613056;            // states + biases

  float* combined = R1;
  float* enc_out  = R1;
  float* seq1     = R2;
  float* dseq1    = R2;
  float* dec_out  = R2 + 1572864;
  float* ctxb     = R2 + 3145728;
  float* attn_o   = R2 + 4718592;
  float* z1p      = R2 + 6291456;
  float* postb    = R2 + 7864320;
  float* gxb      = Dd;
  float* qb       = Dd;
  float* kb       = Dd + 1572864;
  float* vb       = Dd + 12582912;
  float* h0s = st, *c0s = st + 65536, *h1s = st + 131072, *c1s = st + 196608;
  float* biasb = st + 262144;

  // packed vsn weights live at the head of Dd (dead before gx is first written)
  unsigned short* hiP = (unsigned short*)Dd;
  unsigned short* miP = hiP + 622592;
  unsigned short* loP = miP + 622592;   // 1,867,776 shorts = 933,888 floats < Dd

  biasprep_kernel<<<8, 256, 0, stream>>>(ebih, ebhh, dbih, dbhh, biasb);

  pack_kernel<<<2432, 256, 0, stream>>>(vfc2w, vgw, cfc1w, cskw, cfc2w, cgw,
                                        hiP, miP, loP);

  vsn_comb_mfma<<<1344, 256, 0, stream>>>(x_g, vfc1w, vfc1b, vfc2b, vgb,
                                          vskw, vskb, vlns, vlnb,
                                          cfc1b, cskb, cfc2b, cgb, clns, clnb,
                                          hiP, miP, loP, combined);

  // encoder: 2 layers x 3 time-chunks of 56
  for (int l = 0; l < 2; ++l){
    const float* Wih = eWih + l*65536;
    const float* Whh = eWhh + l*65536;
    const float* src = (l == 0) ? combined : seq1;
    float* dst = (l == 0) ? seq1 : enc_out;
    float* hs  = (l == 0) ? h0s : h1s;
    float* cs  = (l == 0) ? c0s : c1s;
    for (int c = 0; c < 3; ++c){
      int t0 = c*CHUNK;
      gemm_kernel<<<dim3(448,4), 256, 0, stream>>>(src + (long)t0*128, Wih,
          biasb + l*512, gxb, B_*CHUNK, 512, CHUNK, (long)TE*128, 128, 1);
      lstm_rec_kernel<<<256, 512, 0, stream>>>(gxb, CHUNK, CHUNK*512, 512, Whh,
          hs, cs, (c == 0) ? 1 : 0, dst + (long)t0*128, (long)TE*128);
    }
  }

  // decoder layer 1
  gemm_kernel<<<dim3(8,4), 256, 0, stream>>>(enc_out + (long)167*128, dWih,
      biasb + 1024, gxb, B_, 512, 1, (long)TE*128, 128, 1);
  lstm_rec_kernel<<<256, 512, 0, stream>>>(gxb, TDD, 512, 0, dWhh,
      h0s, c0s, 0, dseq1, (long)TDD*128);

  // decoder layer 2
  gemm_kernel<<<dim3(192,4), 256, 0, stream>>>(dseq1, dWih + 65536,
      biasb + 1536, gxb, B_*TDD, 512, B_*TDD, 0, 128, 1);
  lstm_rec_kernel<<<256, 512, 0, stream>>>(gxb, TDD, TDD*512, 512, dWhh + 65536,
      h1s, c1s, 0, dec_out, (long)TDD*128);

  // attention projections
  gemm_kernel<<<dim3(192,1),  256, 0, stream>>>(dec_out, qkvw,        qkvb,     qb, B_*TDD, 128, B_*TDD, 0, 128, 1);
  gemm_kernel<<<dim3(1344,1), 256, 0, stream>>>(enc_out, qkvw+16384,  qkvb+128, kb, B_*TE,  128, B_*TE,  0, 128, 1);
  gemm_kernel<<<dim3(1344,1), 256, 0, stream>>>(enc_out, qkvw+32768,  qkvb+256, vb, B_*TE,  128, B_*TE,  0, 128, 1);

  attn_kernel<<<2048, 256, 0, stream>>>(qb, kb, vb, ctxb);

  gemm_kernel<<<dim3(192,1), 256, 0, stream>>>(ctxb,   aow,   aob,   attn_o, B_*TDD, 128, B_*TDD, 0, 128, 1);
  gemm_kernel<<<dim3(192,1), 256, 0, stream>>>(attn_o, pfc1w, pfc1b, z1p,    B_*TDD, 128, B_*TDD, 0, 128, 0);

  grn_core_kernel<<<192, 256, 0, stream>>>(z1p, attn_o, pfc2w, pfc2b, pgw, pgb,
                                           plns, plnb, postb, B_*TDD);

  fcout_kernel<<<288, 256, 0, stream>>>(postb, fcw, fcb, (float*)d_out);
}

// Round 7
// 2446.032 us; speedup vs baseline: 1.6360x; 1.0705x over previous
//
#include <hip/hip_runtime.h>
#include <math.h>

// ---------------------------------------------------------------------------
// TemporalFusionTransformer forward. r7: ALL large GEMMs on MFMA
// (bf16 3-way split = fp32-equivalent precision, 6 mfma per K-chunk).
// B=512, F=9, H=128, L=2, NH=4, OUT=6, T_ENC=168, T_DEC=24.
// ws = 46,393,344 floats = 185.6 MB.
// ---------------------------------------------------------------------------

#define DI __device__ __forceinline__

#define B_    512
#define TE    168
#define TDD   24
#define F_    9
#define H_    128
#define OUT_  6
#define CHUNK 56   // 168 = 3*56

typedef __attribute__((ext_vector_type(8))) short bf16x8;
typedef __attribute__((ext_vector_type(4))) float f32x4;

DI float sigmoid_f(float x){ return 1.0f/(1.0f + __expf(-x)); }
DI float tanh_f(float x){
  float xc = fminf(fmaxf(x, -15.0f), 15.0f);
  float t = __expf(2.0f*xc);
  return (t - 1.0f) / (t + 1.0f);
}
DI float elu_f(float x){ return x > 0.0f ? x : (__expf(x) - 1.0f); }
DI float comp4(const float4 v, int u){ return u==0 ? v.x : (u==1 ? v.y : (u==2 ? v.z : v.w)); }

// bf16 RNE conversion + exact 3-way split (hi+mid+lo covers full fp32 mantissa)
DI unsigned short f2bf(float f){
  unsigned u = __float_as_uint(f);
  unsigned r = (u + 0x7fffu + ((u >> 16) & 1u)) >> 16;
  return (unsigned short)r;
}
DI float bf2f(unsigned short h){ return __uint_as_float(((unsigned)h) << 16); }
DI void split3(float v, short& h, short& m, short& l){
  unsigned short a = f2bf(v);
  float r1 = v - bf2f(a);
  unsigned short b = f2bf(r1);
  float r2 = r1 - bf2f(b);
  h = (short)a; m = (short)b; l = (short)f2bf(r2);
}

// ---------------------------------------------------------------------------
// Pack 1: vsn weights (38 matrices 128x128 K-major) -> B-frag planes.
// B-frag mapping: elem (kc,n,lane,j): col=n*16+(lane&15), k=kc*32+(lane>>4)*8+j.
// ---------------------------------------------------------------------------
__global__ void pack_kernel(const float* __restrict__ w2, const float* __restrict__ wg,
                            const float* __restrict__ cfc1w, const float* __restrict__ cskw,
                            const float* __restrict__ cfc2w, const float* __restrict__ cgw,
                            unsigned short* __restrict__ hiP,
                            unsigned short* __restrict__ miP,
                            unsigned short* __restrict__ loP)
{
  int o = blockIdx.x*256 + threadIdx.x;          // 38*16384 = 622592 total
  if (o >= 38*16384) return;
  int m = o >> 14;
  int r = o & 16383;
  int kc   = r >> 12;
  int n    = (r >> 9) & 7;
  int lane = (r >> 3) & 63;
  int j    = r & 7;
  int k = kc*32 + ((lane >> 4) << 3) + j;
  int c = n*16 + (lane & 15);
  const float* src;
  if      (m < 9)   src = w2    + m*16384;
  else if (m < 18)  src = wg    + (m-9)*16384;
  else if (m < 27)  src = cfc1w + (m-18)*16384;
  else if (m < 36)  src = cskw  + (m-27)*16384;
  else if (m == 36) src = cfc2w;
  else              src = cgw;
  float v = src[k*128 + c];
  short h, mm, l; split3(v, h, mm, l);
  hiP[o] = (unsigned short)h;
  miP[o] = (unsigned short)mm;
  loP[o] = (unsigned short)l;
}

// ---------------------------------------------------------------------------
// Pack 2: pipeline weights -> 21 slices of 128 cols each.
// s 0..7:  eWih  (layer s/4, col-slice s%4)   y = x@W^T
// s 8..15: dWih  (layer (s-8)/4, slice %4)    y = x@W^T
// s 16..18: Wq/Wk/Wv (qkvw rows s*128..)      y = x@W^T
// s 19: attn_out_w                            y = x@W^T
// s 20: post_fc1_w                            y = x@W (direct)
// ---------------------------------------------------------------------------
__global__ void pack2_kernel(const float* __restrict__ eWih, const float* __restrict__ dWih,
                             const float* __restrict__ qkvw, const float* __restrict__ aow,
                             const float* __restrict__ pfc1w,
                             unsigned short* __restrict__ hiP,
                             unsigned short* __restrict__ miP,
                             unsigned short* __restrict__ loP)
{
  int o = blockIdx.x*256 + threadIdx.x;          // 21*16384 = 344064 total
  if (o >= 21*16384) return;
  int s = o >> 14;
  int r = o & 16383;
  int kc   = r >> 12;
  int n    = (r >> 9) & 7;
  int lane = (r >> 3) & 63;
  int j    = r & 7;
  int k = kc*32 + ((lane >> 4) << 3) + j;
  int c = n*16 + (lane & 15);
  float v;
  if (s < 8){
    int l = s >> 2, cs = s & 3;
    v = eWih[(long)l*65536 + (long)(cs*128 + c)*128 + k];
  } else if (s < 16){
    int l = (s-8) >> 2, cs = (s-8) & 3;
    v = dWih[(long)l*65536 + (long)(cs*128 + c)*128 + k];
  } else if (s < 19){
    v = qkvw[(long)((s-16)*128 + c)*128 + k];
  } else if (s == 19){
    v = aow[(long)c*128 + k];
  } else {
    v = pfc1w[(long)k*128 + c];
  }
  short h, mm, l; split3(v, h, mm, l);
  hiP[o] = (unsigned short)h;
  miP[o] = (unsigned short)mm;
  loP[o] = (unsigned short)l;
}

// stage one matrix's 3 planes for one kc (3 x 8KB) into LDS, 256 threads
DI void stage3(const unsigned short* __restrict__ hiP,
               const unsigned short* __restrict__ miP,
               const unsigned short* __restrict__ loP,
               int mat, int kc, unsigned short* Bs, int tid)
{
  long off = (long)mat*16384 + kc*4096;
  const unsigned short* s0 = hiP + off;
  const unsigned short* s1 = miP + off;
  const unsigned short* s2 = loP + off;
  *(uint4*)&Bs[0*4096 + tid*8]        = *(const uint4*)&s0[tid*8];
  *(uint4*)&Bs[0*4096 + 2048 + tid*8] = *(const uint4*)&s0[2048 + tid*8];
  *(uint4*)&Bs[1*4096 + tid*8]        = *(const uint4*)&s1[tid*8];
  *(uint4*)&Bs[1*4096 + 2048 + tid*8] = *(const uint4*)&s1[2048 + tid*8];
  *(uint4*)&Bs[2*4096 + tid*8]        = *(const uint4*)&s2[tid*8];
  *(uint4*)&Bs[2*4096 + 2048 + tid*8] = *(const uint4*)&s2[2048 + tid*8];
}

// 6-mfma split-product accumulate over 8 column tiles for one kc
DI void gemm6(const unsigned short* Bs, bf16x8 aH, bf16x8 aM, bf16x8 aL,
              f32x4 acc[8], int lane)
{
  #pragma unroll
  for (int n = 0; n < 8; ++n){
    bf16x8 bH = *(const bf16x8*)&Bs[0*4096 + n*512 + lane*8];
    bf16x8 bM = *(const bf16x8*)&Bs[1*4096 + n*512 + lane*8];
    bf16x8 bL = *(const bf16x8*)&Bs[2*4096 + n*512 + lane*8];
    acc[n] = __builtin_amdgcn_mfma_f32_16x16x32_bf16(aH, bH, acc[n], 0,0,0);
    acc[n] = __builtin_amdgcn_mfma_f32_16x16x32_bf16(aH, bM, acc[n], 0,0,0);
    acc[n] = __builtin_amdgcn_mfma_f32_16x16x32_bf16(aM, bH, acc[n], 0,0,0);
    acc[n] = __builtin_amdgcn_mfma_f32_16x16x32_bf16(aM, bM, acc[n], 0,0,0);
    acc[n] = __builtin_amdgcn_mfma_f32_16x16x32_bf16(aH, bL, acc[n], 0,0,0);
    acc[n] = __builtin_amdgcn_mfma_f32_16x16x32_bf16(aL, bH, acc[n], 0,0,0);
  }
}

// ---------------------------------------------------------------------------
// Generic MFMA GEMM: C[M, n0:n0+128] = A @ Bslice(mat) + bias.
// A rows: r -> A + (r/a_group)*a_group_stride + (r%a_group)*lda (fp32 global).
// Block 64 rows x 128 cols, 4 waves; wave w owns rows [w*16, w*16+16).
// ---------------------------------------------------------------------------
__global__ __launch_bounds__(256, 2) void mfma_gemm(
    const float* __restrict__ A,
    const unsigned short* __restrict__ hiP, const unsigned short* __restrict__ miP,
    const unsigned short* __restrict__ loP, int matBase,
    const float* __restrict__ bias, float* __restrict__ Cout,
    int M, int ldc, int a_group, long a_group_stride, int lda)
{
  __shared__ __align__(16) unsigned short Bs[3*4096];   // 24 KB

  const int tid  = threadIdx.x;
  const int wave = tid >> 6;
  const int lane = tid & 63;
  const int g16  = lane >> 4;
  const int l16  = lane & 15;
  const int row0 = blockIdx.x * 64;
  const int n0   = blockIdx.y * 128;
  const int mat  = matBase + blockIdx.y;

  long r = row0 + wave*16 + l16;        // A-frag source row
  const bool valid = r < M;
  long bg = r / a_group, tt = r - bg*a_group;
  const float* ap = A + bg*a_group_stride + tt*(long)lda;

  const f32x4 z4 = {0.f,0.f,0.f,0.f};
  f32x4 acc[8];
  #pragma unroll
  for (int n = 0; n < 8; ++n) acc[n] = z4;

  for (int kc = 0; kc < 4; ++kc){
    __syncthreads();
    stage3(hiP, miP, loP, mat, kc, Bs, tid);
    bf16x8 aH, aM, aL;
    int k0 = kc*32 + (g16 << 3);
    float4 v0 = valid ? *(const float4*)(ap + k0)     : make_float4(0,0,0,0);
    float4 v1 = valid ? *(const float4*)(ap + k0 + 4) : make_float4(0,0,0,0);
    #pragma unroll
    for (int j = 0; j < 8; ++j){
      float v = (j < 4) ? comp4(v0, j) : comp4(v1, j-4);
      short sh, sm, sl; split3(v, sh, sm, sl);
      aH[j] = sh; aM[j] = sm; aL[j] = sl;
    }
    __syncthreads();
    gemm6(Bs, aH, aM, aL, acc, lane);
  }

  // C-frag: row = (lane>>4)*4+reg, col = n*16+(lane&15)
  #pragma unroll
  for (int n = 0; n < 8; ++n){
    int c = n0 + n*16 + l16;
    float bv = bias[c];
    #pragma unroll
    for (int reg = 0; reg < 4; ++reg){
      long rr = row0 + wave*16 + (g16 << 2) + reg;
      if (rr < M) Cout[rr*(long)ldc + c] = acc[n][reg] + bv;
    }
  }
}

// ---------------------------------------------------------------------------
// Kernel 1 (MFMA): fused VSN + complete comb-GRN. (unchanged from r6)
// ---------------------------------------------------------------------------
__global__ __launch_bounds__(256, 2) void vsn_comb_mfma(
    const float* __restrict__ x,
    const float* __restrict__ w1,  const float* __restrict__ b1,
    const float* __restrict__ b2,  const float* __restrict__ bg,
    const float* __restrict__ wsk, const float* __restrict__ bsk,
    const float* __restrict__ lns, const float* __restrict__ lnb,
    const float* __restrict__ cfc1b, const float* __restrict__ cskb,
    const float* __restrict__ cfc2b, const float* __restrict__ cgb,
    const float* __restrict__ clns,  const float* __restrict__ clnb,
    const unsigned short* __restrict__ hiP,
    const unsigned short* __restrict__ miP,
    const unsigned short* __restrict__ loP,
    float* __restrict__ outp)
{
  __shared__ __align__(16) float Ht[64*132];
  __shared__ __align__(16) unsigned short Bs[3*4096];
  __shared__ float vecs[8*128];
  __shared__ float xcol[64];

  const int tid  = threadIdx.x;
  const int wave = tid >> 6;
  const int lane = tid & 63;
  const int g16  = lane >> 4;
  const int l16  = lane & 15;
  const int arow = wave*16 + l16;
  const int row0 = blockIdx.x * 64;

  const f32x4 z4 = {0.f, 0.f, 0.f, 0.f};
  f32x4 acc1[8], accS[8];
  #pragma unroll
  for (int n = 0; n < 8; ++n){ acc1[n] = z4; accS[n] = z4; }

  for (int f = 0; f < F_; ++f){
    __syncthreads();
    if (tid < 64){
      int r = row0 + tid;
      int b = r / TE, t = r - b*TE;
      xcol[tid] = x[((long)b*192 + t)*F_ + f];
    } else if (tid >= 128){
      int c = tid - 128;
      vecs[0*128+c] = w1 [f*128+c];
      vecs[1*128+c] = b1 [f*128+c];
      vecs[2*128+c] = b2 [f*128+c];
      vecs[3*128+c] = bg [f*128+c];
      vecs[4*128+c] = wsk[f*128+c];
      vecs[5*128+c] = bsk[f*128+c];
      vecs[6*128+c] = lns[f*128+c];
      vecs[7*128+c] = lnb[f*128+c];
    }
    __syncthreads();

    f32x4 T2[8], Gg[8];
    #pragma unroll
    for (int n = 0; n < 8; ++n){ T2[n] = z4; Gg[n] = z4; }

    for (int kc = 0; kc < 4; ++kc){
      __syncthreads();
      stage3(hiP, miP, loP, f, kc, Bs, tid);
      float xv = xcol[arow];
      int k0 = kc*32 + (g16 << 3);
      bf16x8 aH, aM, aL;
      #pragma unroll
      for (int j = 0; j < 8; ++j){
        float h = elu_f(fmaf(xv, vecs[0*128 + k0 + j], vecs[1*128 + k0 + j]));
        short sh, sm, sl; split3(h, sh, sm, sl);
        aH[j] = sh; aM[j] = sm; aL[j] = sl;
      }
      __syncthreads();
      gemm6(Bs, aH, aM, aL, T2, lane);
      __syncthreads();
      stage3(hiP, miP, loP, 9+f, kc, Bs, tid);
      __syncthreads();
      gemm6(Bs, aH, aM, aL, Gg, lane);
    }

    #pragma unroll
    for (int n = 0; n < 8; ++n){
      int c = n*16 + l16;
      float b2c = vecs[2*128+c], bgc = vecs[3*128+c];
      float wkc = vecs[4*128+c], bkc = vecs[5*128+c];
      #pragma unroll
      for (int r = 0; r < 4; ++r){
        float xv = xcol[wave*16 + (g16 << 2) + r];
        float hv = T2[n][r] + b2c;
        float gv = sigmoid_f(Gg[n][r] + bgc);
        T2[n][r] = fmaf(xv, wkc, bkc) + hv*gv;
      }
    }
    #pragma unroll
    for (int r = 0; r < 4; ++r){
      float s = 0.f;
      #pragma unroll
      for (int n = 0; n < 8; ++n) s += T2[n][r];
      #pragma unroll
      for (int m = 1; m < 16; m <<= 1) s += __shfl_xor(s, m, 64);
      float mu = s * (1.0f/128.0f);
      float vs = 0.f;
      #pragma unroll
      for (int n = 0; n < 8; ++n){ float d = T2[n][r]-mu; vs += d*d; }
      #pragma unroll
      for (int m = 1; m < 16; m <<= 1) vs += __shfl_xor(vs, m, 64);
      float rstd = rsqrtf(vs * (1.0f/128.0f) + 1e-5f);
      #pragma unroll
      for (int n = 0; n < 8; ++n){
        int c = n*16 + l16;
        T2[n][r] = (T2[n][r]-mu)*rstd*vecs[6*128+c] + vecs[7*128+c];
      }
    }
    #pragma unroll
    for (int n = 0; n < 8; ++n)
      #pragma unroll
      for (int r = 0; r < 4; ++r)
        Ht[(wave*16 + (g16<<2) + r)*132 + n*16 + l16] = T2[n][r];

    for (int kc = 0; kc < 4; ++kc){
      __syncthreads();
      stage3(hiP, miP, loP, 18+f, kc, Bs, tid);
      bf16x8 aH, aM, aL;
      {
        const float* hp = &Ht[arow*132 + kc*32 + (g16 << 3)];
        float4 v0 = *(const float4*)hp;
        float4 v1 = *(const float4*)(hp + 4);
        #pragma unroll
        for (int j = 0; j < 8; ++j){
          float v = (j < 4) ? comp4(v0, j) : comp4(v1, j-4);
          short sh, sm, sl; split3(v, sh, sm, sl);
          aH[j] = sh; aM[j] = sm; aL[j] = sl;
        }
      }
      __syncthreads();
      gemm6(Bs, aH, aM, aL, acc1, lane);
      __syncthreads();
      stage3(hiP, miP, loP, 27+f, kc, Bs, tid);
      __syncthreads();
      gemm6(Bs, aH, aM, aL, accS, lane);
    }
  }

  #pragma unroll
  for (int n = 0; n < 8; ++n){
    int c = n*16 + l16;
    float b1c = cfc1b[c], skc = cskb[c];
    #pragma unroll
    for (int r = 0; r < 4; ++r){
      Ht[(wave*16 + (g16<<2) + r)*132 + c] = elu_f(acc1[n][r] + b1c);
      accS[n][r] += skc;
    }
  }
  f32x4 T2[8], Gg[8];
  #pragma unroll
  for (int n = 0; n < 8; ++n){ T2[n] = z4; Gg[n] = z4; }

  for (int kc = 0; kc < 4; ++kc){
    __syncthreads();
    stage3(hiP, miP, loP, 36, kc, Bs, tid);
    bf16x8 aH, aM, aL;
    {
      const float* hp = &Ht[arow*132 + kc*32 + (g16 << 3)];
      float4 v0 = *(const float4*)hp;
      float4 v1 = *(const float4*)(hp + 4);
      #pragma unroll
      for (int j = 0; j < 8; ++j){
        float v = (j < 4) ? comp4(v0, j) : comp4(v1, j-4);
        short sh, sm, sl; split3(v, sh, sm, sl);
        aH[j] = sh; aM[j] = sm; aL[j] = sl;
      }
    }
    __syncthreads();
    gemm6(Bs, aH, aM, aL, T2, lane);
    __syncthreads();
    stage3(hiP, miP, loP, 37, kc, Bs, tid);
    __syncthreads();
    gemm6(Bs, aH, aM, aL, Gg, lane);
  }

  #pragma unroll
  for (int n = 0; n < 8; ++n){
    int c = n*16 + l16;
    float f2b = cfc2b[c], gbb = cgb[c];
    #pragma unroll
    for (int r = 0; r < 4; ++r){
      float hv = (T2[n][r] + f2b) * sigmoid_f(Gg[n][r] + gbb);
      T2[n][r] = accS[n][r] + hv;
    }
  }
  #pragma unroll
  for (int r = 0; r < 4; ++r){
    float s = 0.f;
    #pragma unroll
    for (int n = 0; n < 8; ++n) s += T2[n][r];
    #pragma unroll
    for (int m = 1; m < 16; m <<= 1) s += __shfl_xor(s, m, 64);
    float mu = s * (1.0f/128.0f);
    float vs = 0.f;
    #pragma unroll
    for (int n = 0; n < 8; ++n){ float d = T2[n][r]-mu; vs += d*d; }
    #pragma unroll
    for (int m = 1; m < 16; m <<= 1) vs += __shfl_xor(vs, m, 64);
    float rstd = rsqrtf(vs * (1.0f/128.0f) + 1e-5f);
    long rr = row0 + wave*16 + (g16<<2) + r;
    #pragma unroll
    for (int n = 0; n < 8; ++n){
      int c = n*16 + l16;
      outp[rr*128 + c] = (T2[n][r]-mu)*rstd*clns[c] + clnb[c];
    }
  }
}

// ---------------------------------------------------------------------------
// fp32 GEMM microkernel (used by grn_core only)
// ---------------------------------------------------------------------------
DI void gemm_tile_2(const float* Ht, const float* WtA, const float* WtB,
                    float accA[4][8], float accB[4][8], int tr, int tc, int kt)
{
  #pragma unroll
  for (int k4 = 0; k4 < 8; ++k4){
    float4 a4[4];
    #pragma unroll
    for (int i = 0; i < 4; ++i)
      a4[i] = *(const float4*)&Ht[(tr*4+i)*132 + kt*32 + k4*4];
    #pragma unroll
    for (int u = 0; u < 4; ++u){
      float4 bAlo = *(const float4*)&WtA[(k4*4+u)*132 + tc*8];
      float4 bAhi = *(const float4*)&WtA[(k4*4+u)*132 + tc*8 + 4];
      float4 bBlo = *(const float4*)&WtB[(k4*4+u)*132 + tc*8];
      float4 bBhi = *(const float4*)&WtB[(k4*4+u)*132 + tc*8 + 4];
      #pragma unroll
      for (int i = 0; i < 4; ++i){
        float av = comp4(a4[i], u);
        #pragma unroll
        for (int j = 0; j < 8; ++j){
          float bA = (j < 4) ? comp4(bAlo, j) : comp4(bAhi, j-4);
          float bB = (j < 4) ? comp4(bBlo, j) : comp4(bBhi, j-4);
          accA[i][j] = fmaf(av, bA, accA[i][j]);
          accB[i][j] = fmaf(av, bB, accB[i][j]);
        }
      }
    }
  }
}

// ---------------------------------------------------------------------------
// Kernel 2: GRN core (post-GRN, M=12288)
// ---------------------------------------------------------------------------
__global__ __launch_bounds__(256, 2) void grn_core_kernel(
    const float* __restrict__ Z1, const float* __restrict__ S,
    const float* __restrict__ fc2w, const float* __restrict__ fc2b,
    const float* __restrict__ gw,   const float* __restrict__ gb,
    const float* __restrict__ lns,  const float* __restrict__ lnb,
    float* __restrict__ outp, int M)
{
  __shared__ float Ht[64*132];
  __shared__ float WtA[32*132];
  __shared__ float WtB[32*132];

  const int tid = threadIdx.x;
  const int tr = tid >> 4, tc = tid & 15;
  const int row0 = blockIdx.x * 64;

  #pragma unroll
  for (int i = 0; i < 8; ++i){
    int fi = tid + i*256;
    int row = fi >> 5, c4 = (fi & 31)*4;
    long r = row0 + row;
    float4 z = make_float4(0.f,0.f,0.f,0.f);
    if (r < M) z = *(const float4*)&Z1[r*128 + c4];
    z.x = elu_f(z.x); z.y = elu_f(z.y); z.z = elu_f(z.z); z.w = elu_f(z.w);
    *(float4*)&Ht[row*132 + c4] = z;
  }

  float T2[4][8], Gg[4][8];
  #pragma unroll
  for (int i = 0; i < 4; ++i)
    #pragma unroll
    for (int j = 0; j < 8; ++j){ T2[i][j] = 0.f; Gg[i][j] = 0.f; }

  for (int kt = 0; kt < 4; ++kt){
    __syncthreads();
    #pragma unroll
    for (int i = 0; i < 4; ++i){
      int li = tid + i*256;
      int kk = li >> 5, c4 = (li & 31)*4;
      *(float4*)&WtA[kk*132 + c4] = *(const float4*)&fc2w[(kt*32+kk)*128 + c4];
      *(float4*)&WtB[kk*132 + c4] = *(const float4*)&gw  [(kt*32+kk)*128 + c4];
    }
    __syncthreads();
    gemm_tile_2(Ht, WtA, WtB, T2, Gg, tr, tc, kt);
  }

  float val[4][8];
  #pragma unroll
  for (int i = 0; i < 4; ++i){
    long r = row0 + tr*4 + i;
    float4 s0 = make_float4(0,0,0,0), s1 = make_float4(0,0,0,0);
    if (r < M){
      s0 = *(const float4*)&S[r*128 + tc*8];
      s1 = *(const float4*)&S[r*128 + tc*8 + 4];
    }
    #pragma unroll
    for (int j = 0; j < 8; ++j){
      int c = tc*8 + j;
      float sv = (j < 4) ? comp4(s0, j) : comp4(s1, j-4);
      float hv = (T2[i][j] + fc2b[c]) * sigmoid_f(Gg[i][j] + gb[c]);
      val[i][j] = sv + hv;
    }
  }
  #pragma unroll
  for (int i = 0; i < 4; ++i){
    float s = 0.f;
    #pragma unroll
    for (int j = 0; j < 8; ++j) s += val[i][j];
    #pragma unroll
    for (int m = 1; m < 16; m <<= 1) s += __shfl_xor(s, m, 64);
    float mu = s * (1.0f/128.0f);
    float vs = 0.f;
    #pragma unroll
    for (int j = 0; j < 8; ++j){ float d = val[i][j]-mu; vs += d*d; }
    #pragma unroll
    for (int m = 1; m < 16; m <<= 1) vs += __shfl_xor(vs, m, 64);
    float rstd = rsqrtf(vs * (1.0f/128.0f) + 1e-5f);
    long r = row0 + tr*4 + i;
    if (r < M){
      #pragma unroll
      for (int j = 0; j < 8; ++j){
        int c = tc*8 + j;
        outp[r*128 + c] = (val[i][j]-mu)*rstd*lns[c] + lnb[c];
      }
    }
  }
}

// ---------------------------------------------------------------------------
// Kernel 4: LSTM recurrence (batch-parallel, Whh in VGPRs, readlane broadcast)
// ---------------------------------------------------------------------------
__global__ __launch_bounds__(512, 2) void lstm_rec_kernel(
    const float* __restrict__ gx, int nsteps, int gbs, int gts,
    const float* __restrict__ Whh,
    float* __restrict__ h_state, float* __restrict__ c_state, int init_zero,
    float* __restrict__ seq_out, long seq_b_stride)
{
  __shared__ float hbuf[2][128];
  __shared__ float act[4][2][128];

  const int tid = threadIdx.x;
  const int lane = tid & 63;
  const int b0 = blockIdx.x * 2;
  const int type = tid >> 7;
  const int u = tid & 127;

  float4 w[32];
  #pragma unroll
  for (int i = 0; i < 32; ++i)
    w[i] = *(const float4*)&Whh[(long)tid*128 + i*4];

  if (tid < 256){
    int bi = tid >> 7, uu = tid & 127;
    hbuf[bi][uu] = init_zero ? 0.f : h_state[(long)(b0+bi)*128 + uu];
  }
  float creg0 = 0.f, creg1 = 0.f;
  if (tid < 128 && !init_zero){
    creg0 = c_state[(long)b0*128 + tid];
    creg1 = c_state[(long)(b0+1)*128 + tid];
  }

  for (int t = 0; t < nsteps; ++t){
    __syncthreads();
    float hA0 = hbuf[0][lane],    hA1 = hbuf[0][64+lane];
    float hB0 = hbuf[1][lane],    hB1 = hbuf[1][64+lane];
    float acc0  = gx[(long)b0*gbs     + (long)t*gts + tid];
    float acc1  = gx[(long)(b0+1)*gbs + (long)t*gts + tid];
    float acc0b = 0.f, acc1b = 0.f;
    #pragma unroll
    for (int j = 0; j < 64; ++j){
      float wv = comp4(w[j>>2], j&3);
      float s0 = __int_as_float(__builtin_amdgcn_readlane(__float_as_int(hA0), j));
      float s1 = __int_as_float(__builtin_amdgcn_readlane(__float_as_int(hB0), j));
      acc0 = fmaf(wv, s0, acc0);
      acc1 = fmaf(wv, s1, acc1);
    }
    #pragma unroll
    for (int j = 0; j < 64; ++j){
      float wv = comp4(w[16 + (j>>2)], j&3);
      float s0 = __int_as_float(__builtin_amdgcn_readlane(__float_as_int(hA1), j));
      float s1 = __int_as_float(__builtin_amdgcn_readlane(__float_as_int(hB1), j));
      acc0b = fmaf(wv, s0, acc0b);
      acc1b = fmaf(wv, s1, acc1b);
    }
    acc0 += acc0b; acc1 += acc1b;

    float a0, a1;
    if (type == 2){ a0 = tanh_f(acc0); a1 = tanh_f(acc1); }
    else          { a0 = sigmoid_f(acc0); a1 = sigmoid_f(acc1); }
    act[type][0][u] = a0;
    act[type][1][u] = a1;
    __syncthreads();
    if (tid < 128){
      float cn0 = act[1][0][u]*creg0 + act[0][0][u]*act[2][0][u];
      float hn0 = act[3][0][u]*tanh_f(cn0);
      creg0 = cn0;
      float cn1 = act[1][1][u]*creg1 + act[0][1][u]*act[2][1][u];
      float hn1 = act[3][1][u]*tanh_f(cn1);
      creg1 = cn1;
      hbuf[0][u] = hn0;
      hbuf[1][u] = hn1;
      seq_out[(long)b0*seq_b_stride     + (long)t*128 + u] = hn0;
      seq_out[(long)(b0+1)*seq_b_stride + (long)t*128 + u] = hn1;
    }
  }
  __syncthreads();
  if (tid < 256){
    int bi = tid >> 7, uu = tid & 127;
    h_state[(long)(b0+bi)*128 + uu] = hbuf[bi][uu];
  }
  if (tid < 128){
    c_state[(long)b0*128 + tid]     = creg0;
    c_state[(long)(b0+1)*128 + tid] = creg1;
  }
}

// ---------------------------------------------------------------------------
// Kernel 5: attention core per (batch, head)
// ---------------------------------------------------------------------------
__global__ __launch_bounds__(256) void attn_kernel(
    const float* __restrict__ q, const float* __restrict__ k,
    const float* __restrict__ v, float* __restrict__ ctx)
{
  __shared__ float kb[168*33];
  __shared__ float vbuf[168*33];
  __shared__ float qb[24*33];
  __shared__ float sc[24*172];

  const int tid = threadIdx.x;
  const int bh = blockIdx.x;
  const int b = bh >> 2, h = bh & 3;

  for (int l = tid; l < 1344; l += 256){
    int t = l >> 3, d4 = (l & 7)*4;
    float4 kv = *(const float4*)&k[((long)(b*168 + t))*128 + h*32 + d4];
    kb[t*33+d4+0] = kv.x; kb[t*33+d4+1] = kv.y; kb[t*33+d4+2] = kv.z; kb[t*33+d4+3] = kv.w;
    float4 vv = *(const float4*)&v[((long)(b*168 + t))*128 + h*32 + d4];
    vbuf[t*33+d4+0] = vv.x; vbuf[t*33+d4+1] = vv.y; vbuf[t*33+d4+2] = vv.z; vbuf[t*33+d4+3] = vv.w;
  }
  if (tid < 192){
    int t = tid >> 3, d4 = (tid & 7)*4;
    float4 qv = *(const float4*)&q[((long)(b*24 + t))*128 + h*32 + d4];
    qb[t*33+d4+0] = qv.x; qb[t*33+d4+1] = qv.y; qb[t*33+d4+2] = qv.z; qb[t*33+d4+3] = qv.w;
  }
  __syncthreads();

  if (tid < 168){
    int j = tid;
    for (int i = 0; i < 24; ++i){
      float s = 0.f;
      #pragma unroll
      for (int d = 0; d < 32; ++d)
        s = fmaf(qb[i*33+d], kb[j*33+d], s);
      sc[i*172 + j] = s * 0.17677669529663687f;
    }
  }
  __syncthreads();

  const int lane = tid & 63;
  const int wv = tid >> 6;
  for (int m = 0; m < 6; ++m){
    int i = wv + 4*m;
    float v0 = sc[i*172 + lane];
    float v1 = sc[i*172 + 64 + lane];
    float v2 = (lane < 40) ? sc[i*172 + 128 + lane] : -1e30f;
    float mx = fmaxf(v0, fmaxf(v1, v2));
    #pragma unroll
    for (int s = 1; s < 64; s <<= 1) mx = fmaxf(mx, __shfl_xor(mx, s, 64));
    float e0 = __expf(v0 - mx), e1 = __expf(v1 - mx);
    float e2 = (lane < 40) ? __expf(v2 - mx) : 0.f;
    float sm = e0 + e1 + e2;
    #pragma unroll
    for (int s = 1; s < 64; s <<= 1) sm += __shfl_xor(sm, s, 64);
    float inv = 1.0f / sm;
    sc[i*172 + lane]      = e0*inv;
    sc[i*172 + 64 + lane] = e1*inv;
    if (lane < 40) sc[i*172 + 128 + lane] = e2*inv;
  }
  __syncthreads();

  #pragma unroll
  for (int kk = 0; kk < 3; ++kk){
    int o = tid + kk*256;
    int i = o >> 5, d = o & 31;
    float s = 0.f;
    for (int j = 0; j < 168; ++j)
      s = fmaf(sc[i*172 + j], vbuf[j*33 + d], s);
    ctx[((long)(b*24 + i))*128 + h*32 + d] = s;
  }
}

// ---------------------------------------------------------------------------
// Kernel 6: final projection (12288,128)->(12288,6)
// ---------------------------------------------------------------------------
__global__ void fcout_kernel(const float* __restrict__ post,
                             const float* __restrict__ w,
                             const float* __restrict__ bias,
                             float* __restrict__ out)
{
  int gid = blockIdx.x*256 + threadIdx.x;
  if (gid >= 12288*OUT_) return;
  int r = gid / OUT_, o = gid - r*OUT_;
  float s = bias[o];
  #pragma unroll 8
  for (int kk = 0; kk < 128; ++kk)
    s = fmaf(post[(long)r*128 + kk], w[kk*OUT_ + o], s);
  out[gid] = s;
}

// Kernel 7: bias sums
__global__ void biasprep_kernel(const float* __restrict__ ebih, const float* __restrict__ ebhh,
                                const float* __restrict__ dbih, const float* __restrict__ dbhh,
                                float* __restrict__ outb)
{
  int i = blockIdx.x*256 + threadIdx.x;
  if (i < 1024)       outb[i] = ebih[i] + ebhh[i];
  else if (i < 2048)  outb[i] = dbih[i-1024] + dbhh[i-1024];
}

// ---------------------------------------------------------------------------
extern "C" void kernel_launch(void* const* d_in, const int* in_sizes, int n_in,
                              void* d_out, int out_size, void* d_ws, size_t ws_size,
                              hipStream_t stream)
{
  const float* x_g   = (const float*)d_in[0];
  const float* vfc1w = (const float*)d_in[1];
  const float* vfc1b = (const float*)d_in[2];
  const float* vfc2w = (const float*)d_in[3];
  const float* vfc2b = (const float*)d_in[4];
  const float* vgw   = (const float*)d_in[5];
  const float* vgb   = (const float*)d_in[6];
  const float* vskw  = (const float*)d_in[7];
  const float* vskb  = (const float*)d_in[8];
  const float* vlns  = (const float*)d_in[9];
  const float* vlnb  = (const float*)d_in[10];
  const float* cfc1w = (const float*)d_in[11];
  const float* cfc1b = (const float*)d_in[12];
  const float* cfc2w = (const float*)d_in[13];
  const float* cfc2b = (const float*)d_in[14];
  const float* cgw   = (const float*)d_in[15];
  const float* cgb   = (const float*)d_in[16];
  const float* cskw  = (const float*)d_in[17];
  const float* cskb  = (const float*)d_in[18];
  const float* clns  = (const float*)d_in[19];
  const float* clnb  = (const float*)d_in[20];
  const float* eWih  = (const float*)d_in[21];
  const float* eWhh  = (const float*)d_in[22];
  const float* ebih  = (const float*)d_in[23];
  const float* ebhh  = (const float*)d_in[24];
  const float* dWih  = (const float*)d_in[25];
  const float* dWhh  = (const float*)d_in[26];
  const float* dbih  = (const float*)d_in[27];
  const float* dbhh  = (const float*)d_in[28];
  const float* qkvw  = (const float*)d_in[29];
  const float* qkvb  = (const float*)d_in[30];
  const float* aow   = (const float*)d_in[31];
  const float* aob   = (const float*)d_in[32];
  const float* pfc1w = (const float*)d_in[33];
  const float* pfc1b = (const float*)d_in[34];
  const float* pfc2w = (const float*)d_in[35];
  const float* pfc2b = (const float*)d_in[36];
  const float* pgw   = (const float*)d_in[37];
  const float* pgb   = (const float*)d_in[38];
  const float* plns  = (const float*)d_in[39];
  const float* plnb  = (const float*)d_in[40];
  const float* fcw   = (const float*)d_in[41];
  const float* fcb   = (const float*)d_in[42];

  float* ws = (float*)d_ws;
  // layout: R1(11,010,048) R2(11,010,048) Dd(23,592,960) st(264,192) pk2(516,096)
  float* R1 = ws;
  float* R2 = ws + 11010048;
  float* Dd = ws + 22020096;
  float* st = ws + 45613056;

  float* combined = R1;
  float* enc_out  = R1;
  float* seq1     = R2;
  float* dseq1    = R2;
  float* dec_out  = R2 + 1572864;
  float* ctxb     = R2 + 3145728;
  float* attn_o   = R2 + 4718592;
  float* z1p      = R2 + 6291456;
  float* postb    = R2 + 7864320;
  float* gxb      = Dd;
  float* qb       = Dd;
  float* kb       = Dd + 1572864;
  float* vb       = Dd + 12582912;
  float* h0s = st, *c0s = st + 65536, *h1s = st + 131072, *c1s = st + 196608;
  float* biasb = st + 262144;           // 2048 floats

  // vsn packed planes: alias Dd head (dead before gxb first written)
  unsigned short* hiP = (unsigned short*)Dd;
  unsigned short* miP = hiP + 622592;
  unsigned short* loP = miP + 622592;

  // pipeline packed planes: persistent, after st
  unsigned short* hiP2 = (unsigned short*)(st + 264192);
  unsigned short* miP2 = hiP2 + 344064;
  unsigned short* loP2 = miP2 + 344064;   // ends at ws + 46,393,344 floats

  biasprep_kernel<<<8, 256, 0, stream>>>(ebih, ebhh, dbih, dbhh, biasb);
  pack_kernel<<<2432, 256, 0, stream>>>(vfc2w, vgw, cfc1w, cskw, cfc2w, cgw,
                                        hiP, miP, loP);
  pack2_kernel<<<1344, 256, 0, stream>>>(eWih, dWih, qkvw, aow, pfc1w,
                                         hiP2, miP2, loP2);

  vsn_comb_mfma<<<1344, 256, 0, stream>>>(x_g, vfc1w, vfc1b, vfc2b, vgb,
                                          vskw, vskb, vlns, vlnb,
                                          cfc1b, cskb, cfc2b, cgb, clns, clnb,
                                          hiP, miP, loP, combined);

  // encoder: 2 layers x 3 time-chunks of 56
  for (int l = 0; l < 2; ++l){
    const float* Whh = eWhh + l*65536;
    const float* src = (l == 0) ? combined : seq1;
    float* dst = (l == 0) ? seq1 : enc_out;
    float* hs  = (l == 0) ? h0s : h1s;
    float* cs  = (l == 0) ? c0s : c1s;
    for (int c = 0; c < 3; ++c){
      int t0 = c*CHUNK;
      mfma_gemm<<<dim3(448,4), 256, 0, stream>>>(src + (long)t0*128,
          hiP2, miP2, loP2, l*4, biasb + l*512, gxb,
          B_*CHUNK, 512, CHUNK, (long)TE*128, 128);
      lstm_rec_kernel<<<256, 512, 0, stream>>>(gxb, CHUNK, CHUNK*512, 512, Whh,
          hs, cs, (c == 0) ? 1 : 0, dst + (long)t0*128, (long)TE*128);
    }
  }

  // decoder layer 1: input = enc_out[:,167,:] repeated
  mfma_gemm<<<dim3(8,4), 256, 0, stream>>>(enc_out + (long)167*128,
      hiP2, miP2, loP2, 8, biasb + 1024, gxb,
      B_, 512, 1, (long)TE*128, 128);
  lstm_rec_kernel<<<256, 512, 0, stream>>>(gxb, TDD, 512, 0, dWhh,
      h0s, c0s, 0, dseq1, (long)TDD*128);

  // decoder layer 2
  mfma_gemm<<<dim3(192,4), 256, 0, stream>>>(dseq1,
      hiP2, miP2, loP2, 12, biasb + 1536, gxb,
      B_*TDD, 512, B_*TDD, 0, 128);
  lstm_rec_kernel<<<256, 512, 0, stream>>>(gxb, TDD, TDD*512, 512, dWhh + 65536,
      h1s, c1s, 0, dec_out, (long)TDD*128);

  // attention projections
  mfma_gemm<<<dim3(192,1),  256, 0, stream>>>(dec_out, hiP2, miP2, loP2, 16,
      qkvb,     qb, B_*TDD, 128, B_*TDD, 0, 128);
  mfma_gemm<<<dim3(1344,1), 256, 0, stream>>>(enc_out, hiP2, miP2, loP2, 17,
      qkvb+128, kb, B_*TE,  128, B_*TE,  0, 128);
  mfma_gemm<<<dim3(1344,1), 256, 0, stream>>>(enc_out, hiP2, miP2, loP2, 18,
      qkvb+256, vb, B_*TE,  128, B_*TE,  0, 128);

  attn_kernel<<<2048, 256, 0, stream>>>(qb, kb, vb, ctxb);

  mfma_gemm<<<dim3(192,1), 256, 0, stream>>>(ctxb,   hiP2, miP2, loP2, 19,
      aob,   attn_o, B_*TDD, 128, B_*TDD, 0, 128);
  mfma_gemm<<<dim3(192,1), 256, 0, stream>>>(attn_o, hiP2, miP2, loP2, 20,
      pfc1b, z1p,    B_*TDD, 128, B_*TDD, 0, 128);

  grn_core_kernel<<<192, 256, 0, stream>>>(z1p, attn_o, pfc2w, pfc2b, pgw, pgb,
                                           plns, plnb, postb, B_*TDD);

  fcout_kernel<<<288, 256, 0, stream>>>(postb, fcw, fcb, (float*)d_out);
}

// Round 9
// 1956.636 us; speedup vs baseline: 2.0453x; 1.2501x over previous
//
#include <hip/hip_runtime.h>
#include <math.h>

// ---------------------------------------------------------------------------
// TemporalFusionTransformer forward. r8: 2-way bf16 split (3 mfma / product,
// ~2^-15 rel error, f32-tolerance-safe) + paired-matrix staging (half the
// barriers) + higher mfma_gemm occupancy.
// B=512, F=9, H=128, L=2, NH=4, OUT=6, T_ENC=168, T_DEC=24.
// ws = 46,221,312 floats = 184.9 MB.
// ---------------------------------------------------------------------------

#define DI __device__ __forceinline__

#define B_    512
#define TE    168
#define TDD   24
#define F_    9
#define H_    128
#define OUT_  6
#define CHUNK 56   // 168 = 3*56

typedef __attribute__((ext_vector_type(8))) short bf16x8;
typedef __attribute__((ext_vector_type(4))) float f32x4;

DI float sigmoid_f(float x){ return 1.0f/(1.0f + __expf(-x)); }
DI float tanh_f(float x){
  float xc = fminf(fmaxf(x, -15.0f), 15.0f);
  float t = __expf(2.0f*xc);
  return (t - 1.0f) / (t + 1.0f);
}
DI float elu_f(float x){ return x > 0.0f ? x : (__expf(x) - 1.0f); }
DI float comp4(const float4 v, int u){ return u==0 ? v.x : (u==1 ? v.y : (u==2 ? v.z : v.w)); }

// bf16 RNE + exact 2-way split (hi + lo ~ top 16 mantissa bits)
DI unsigned short f2bf(float f){
  unsigned u = __float_as_uint(f);
  unsigned r = (u + 0x7fffu + ((u >> 16) & 1u)) >> 16;
  return (unsigned short)r;
}
DI float bf2f(unsigned short h){ return __uint_as_float(((unsigned)h) << 16); }
DI void split2(float v, short& h, short& l){
  unsigned short a = f2bf(v);
  float r1 = v - bf2f(a);       // exact (Sterbenz)
  h = (short)a; l = (short)f2bf(r1);
}

// ---------------------------------------------------------------------------
// Pack 1: vsn weights (38 matrices 128x128 K-major) -> B-frag hi/lo planes.
// B-frag elem (kc,n,lane,j): col=n*16+(lane&15), k=kc*32+(lane>>4)*8+j.
// ---------------------------------------------------------------------------
__global__ void pack_kernel(const float* __restrict__ w2, const float* __restrict__ wg,
                            const float* __restrict__ cfc1w, const float* __restrict__ cskw,
                            const float* __restrict__ cfc2w, const float* __restrict__ cgw,
                            unsigned short* __restrict__ hiP,
                            unsigned short* __restrict__ loP)
{
  int o = blockIdx.x*256 + threadIdx.x;          // 38*16384 = 622592 total
  if (o >= 38*16384) return;
  int m = o >> 14;
  int r = o & 16383;
  int kc   = r >> 12;
  int n    = (r >> 9) & 7;
  int lane = (r >> 3) & 63;
  int j    = r & 7;
  int k = kc*32 + ((lane >> 4) << 3) + j;
  int c = n*16 + (lane & 15);
  const float* src;
  if      (m < 9)   src = w2    + m*16384;
  else if (m < 18)  src = wg    + (m-9)*16384;
  else if (m < 27)  src = cfc1w + (m-18)*16384;
  else if (m < 36)  src = cskw  + (m-27)*16384;
  else if (m == 36) src = cfc2w;
  else              src = cgw;
  float v = src[k*128 + c];
  short h, l; split2(v, h, l);
  hiP[o] = (unsigned short)h;
  loP[o] = (unsigned short)l;
}

// ---------------------------------------------------------------------------
// Pack 2: pipeline weights -> 21 slices of 128 cols each (hi/lo planes).
// s 0..7: eWih (layer s/4, col-slice s%4, x@W^T); s 8..15: dWih;
// s 16..18: Wq/Wk/Wv; s 19: attn_out_w (x@W^T); s 20: post_fc1_w (x@W).
// ---------------------------------------------------------------------------
__global__ void pack2_kernel(const float* __restrict__ eWih, const float* __restrict__ dWih,
                             const float* __restrict__ qkvw, const float* __restrict__ aow,
                             const float* __restrict__ pfc1w,
                             unsigned short* __restrict__ hiP,
                             unsigned short* __restrict__ loP)
{
  int o = blockIdx.x*256 + threadIdx.x;          // 21*16384 = 344064 total
  if (o >= 21*16384) return;
  int s = o >> 14;
  int r = o & 16383;
  int kc   = r >> 12;
  int n    = (r >> 9) & 7;
  int lane = (r >> 3) & 63;
  int j    = r & 7;
  int k = kc*32 + ((lane >> 4) << 3) + j;
  int c = n*16 + (lane & 15);
  float v;
  if (s < 8){
    int l = s >> 2, cs = s & 3;
    v = eWih[(long)l*65536 + (long)(cs*128 + c)*128 + k];
  } else if (s < 16){
    int l = (s-8) >> 2, cs = (s-8) & 3;
    v = dWih[(long)l*65536 + (long)(cs*128 + c)*128 + k];
  } else if (s < 19){
    v = qkvw[(long)((s-16)*128 + c)*128 + k];
  } else if (s == 19){
    v = aow[(long)c*128 + k];
  } else {
    v = pfc1w[(long)k*128 + c];
  }
  short h, l; split2(v, h, l);
  hiP[o] = (unsigned short)h;
  loP[o] = (unsigned short)l;
}

// stage TWO matrices' hi/lo planes for one kc (4 x 8KB = 32KB), 256 threads
DI void stagePair(const unsigned short* __restrict__ hiP,
                  const unsigned short* __restrict__ loP,
                  int matA, int matB, int kc, unsigned short* Bs, int tid)
{
  long offA = (long)matA*16384 + kc*4096;
  long offB = (long)matB*16384 + kc*4096;
  *(uint4*)&Bs[0*4096 + tid*8]        = *(const uint4*)&hiP[offA + tid*8];
  *(uint4*)&Bs[0*4096 + 2048 + tid*8] = *(const uint4*)&hiP[offA + 2048 + tid*8];
  *(uint4*)&Bs[1*4096 + tid*8]        = *(const uint4*)&loP[offA + tid*8];
  *(uint4*)&Bs[1*4096 + 2048 + tid*8] = *(const uint4*)&loP[offA + 2048 + tid*8];
  *(uint4*)&Bs[2*4096 + tid*8]        = *(const uint4*)&hiP[offB + tid*8];
  *(uint4*)&Bs[2*4096 + 2048 + tid*8] = *(const uint4*)&hiP[offB + 2048 + tid*8];
  *(uint4*)&Bs[3*4096 + tid*8]        = *(const uint4*)&loP[offB + tid*8];
  *(uint4*)&Bs[3*4096 + 2048 + tid*8] = *(const uint4*)&loP[offB + 2048 + tid*8];
}

// stage ONE matrix's hi/lo planes for one kc (2 x 8KB), 256 threads
DI void stageOne(const unsigned short* __restrict__ hiP,
                 const unsigned short* __restrict__ loP,
                 int mat, int kc, unsigned short* Bs, int tid)
{
  long off = (long)mat*16384 + kc*4096;
  *(uint4*)&Bs[tid*8]               = *(const uint4*)&hiP[off + tid*8];
  *(uint4*)&Bs[2048 + tid*8]        = *(const uint4*)&hiP[off + 2048 + tid*8];
  *(uint4*)&Bs[4096 + tid*8]        = *(const uint4*)&loP[off + tid*8];
  *(uint4*)&Bs[4096 + 2048 + tid*8] = *(const uint4*)&loP[off + 2048 + tid*8];
}

// 3-mfma split-product accumulate (HH + HL + LH) over 8 col tiles.
// BsM: [hi 4096][lo 4096] shorts.
DI void gemm3(const unsigned short* BsM, bf16x8 aH, bf16x8 aL,
              f32x4 acc[8], int lane)
{
  #pragma unroll
  for (int n = 0; n < 8; ++n){
    bf16x8 bH = *(const bf16x8*)&BsM[n*512 + lane*8];
    bf16x8 bL = *(const bf16x8*)&BsM[4096 + n*512 + lane*8];
    acc[n] = __builtin_amdgcn_mfma_f32_16x16x32_bf16(aH, bH, acc[n], 0,0,0);
    acc[n] = __builtin_amdgcn_mfma_f32_16x16x32_bf16(aH, bL, acc[n], 0,0,0);
    acc[n] = __builtin_amdgcn_mfma_f32_16x16x32_bf16(aL, bH, acc[n], 0,0,0);
  }
}

// ---------------------------------------------------------------------------
// Generic MFMA GEMM: C[M, n0:n0+128] = A @ Bslice(mat) + bias.
// A rows: r -> A + (r/a_group)*a_group_stride + (r%a_group)*lda (fp32).
// 16KB LDS, 4 blocks/CU for latency hiding.
// ---------------------------------------------------------------------------
__global__ __launch_bounds__(256, 4) void mfma_gemm(
    const float* __restrict__ A,
    const unsigned short* __restrict__ hiP, const unsigned short* __restrict__ loP,
    int matBase,
    const float* __restrict__ bias, float* __restrict__ Cout,
    int M, int ldc, int a_group, long a_group_stride, int lda)
{
  __shared__ __align__(16) unsigned short Bs[2*4096];   // 16 KB

  const int tid  = threadIdx.x;
  const int wave = tid >> 6;
  const int lane = tid & 63;
  const int g16  = lane >> 4;
  const int l16  = lane & 15;
  const int row0 = blockIdx.x * 64;
  const int n0   = blockIdx.y * 128;
  const int mat  = matBase + blockIdx.y;

  long r = row0 + wave*16 + l16;
  const bool valid = r < M;
  long bg = r / a_group, tt = r - bg*a_group;
  const float* ap = A + bg*a_group_stride + tt*(long)lda;

  const f32x4 z4 = {0.f,0.f,0.f,0.f};
  f32x4 acc[8];
  #pragma unroll
  for (int n = 0; n < 8; ++n) acc[n] = z4;

  for (int kc = 0; kc < 4; ++kc){
    __syncthreads();
    stageOne(hiP, loP, mat, kc, Bs, tid);
    bf16x8 aH, aL;
    int k0 = kc*32 + (g16 << 3);
    float4 v0 = valid ? *(const float4*)(ap + k0)     : make_float4(0,0,0,0);
    float4 v1 = valid ? *(const float4*)(ap + k0 + 4) : make_float4(0,0,0,0);
    #pragma unroll
    for (int j = 0; j < 8; ++j){
      float v = (j < 4) ? comp4(v0, j) : comp4(v1, j-4);
      short sh, sl; split2(v, sh, sl);
      aH[j] = sh; aL[j] = sl;
    }
    __syncthreads();
    gemm3(Bs, aH, aL, acc, lane);
  }

  // C-frag: row = (lane>>4)*4+reg, col = n*16+(lane&15)
  #pragma unroll
  for (int n = 0; n < 8; ++n){
    int c = n0 + n*16 + l16;
    float bv = bias[c];
    #pragma unroll
    for (int reg = 0; reg < 4; ++reg){
      long rr = row0 + wave*16 + (g16 << 2) + reg;
      if (rr < M) Cout[rr*(long)ldc + c] = acc[n][reg] + bv;
    }
  }
}

// ---------------------------------------------------------------------------
// Kernel 1 (MFMA): fused VSN + complete comb-GRN, paired staging, 2-way split.
// Block = 64 rows, 4 waves; wave w owns rows [w*16, w*16+16) (Ht wave-private).
// ---------------------------------------------------------------------------
__global__ __launch_bounds__(256, 2) void vsn_comb_mfma(
    const float* __restrict__ x,
    const float* __restrict__ w1,  const float* __restrict__ b1,
    const float* __restrict__ b2,  const float* __restrict__ bg,
    const float* __restrict__ wsk, const float* __restrict__ bsk,
    const float* __restrict__ lns, const float* __restrict__ lnb,
    const float* __restrict__ cfc1b, const float* __restrict__ cskb,
    const float* __restrict__ cfc2b, const float* __restrict__ cgb,
    const float* __restrict__ clns,  const float* __restrict__ clnb,
    const unsigned short* __restrict__ hiP,
    const unsigned short* __restrict__ loP,
    float* __restrict__ outp)
{
  __shared__ __align__(16) float Ht[64*132];            // 33.8 KB
  __shared__ __align__(16) unsigned short Bs[4*4096];   // 32 KB
  __shared__ float vecs[8*128];                         // 4 KB
  __shared__ float xcol[64];

  const int tid  = threadIdx.x;
  const int wave = tid >> 6;
  const int lane = tid & 63;
  const int g16  = lane >> 4;
  const int l16  = lane & 15;
  const int arow = wave*16 + l16;
  const int row0 = blockIdx.x * 64;

  const f32x4 z4 = {0.f, 0.f, 0.f, 0.f};
  f32x4 acc1[8], accS[8];
  #pragma unroll
  for (int n = 0; n < 8; ++n){ acc1[n] = z4; accS[n] = z4; }

  for (int f = 0; f < F_; ++f){
    __syncthreads();
    if (tid < 64){
      int r = row0 + tid;
      int b = r / TE, t = r - b*TE;
      xcol[tid] = x[((long)b*192 + t)*F_ + f];
    } else if (tid >= 128){
      int c = tid - 128;
      vecs[0*128+c] = w1 [f*128+c];
      vecs[1*128+c] = b1 [f*128+c];
      vecs[2*128+c] = b2 [f*128+c];
      vecs[3*128+c] = bg [f*128+c];
      vecs[4*128+c] = wsk[f*128+c];
      vecs[5*128+c] = bsk[f*128+c];
      vecs[6*128+c] = lns[f*128+c];
      vecs[7*128+c] = lnb[f*128+c];
    }
    __syncthreads();

    f32x4 T2[8], Gg[8];
    #pragma unroll
    for (int n = 0; n < 8; ++n){ T2[n] = z4; Gg[n] = z4; }

    // ---- phase 1: T2,Gg = h1 @ (w2[f], wg[f]) — one staging round per kc --
    for (int kc = 0; kc < 4; ++kc){
      __syncthreads();                  // Bs free
      stagePair(hiP, loP, f, 9+f, kc, Bs, tid);
      float xv = xcol[arow];
      int k0 = kc*32 + (g16 << 3);
      bf16x8 aH, aL;
      #pragma unroll
      for (int j = 0; j < 8; ++j){
        float h = elu_f(fmaf(xv, vecs[0*128 + k0 + j], vecs[1*128 + k0 + j]));
        short sh, sl; split2(h, sh, sl);
        aH[j] = sh; aL[j] = sl;
      }
      __syncthreads();                  // Bs staged
      gemm3(Bs,        aH, aL, T2, lane);
      gemm3(Bs + 8192, aH, aL, Gg, lane);
    }

    // ---- epilogue 1: val = skip + h*sig(g); per-feature LN -> Ht ----
    #pragma unroll
    for (int n = 0; n < 8; ++n){
      int c = n*16 + l16;
      float b2c = vecs[2*128+c], bgc = vecs[3*128+c];
      float wkc = vecs[4*128+c], bkc = vecs[5*128+c];
      #pragma unroll
      for (int r = 0; r < 4; ++r){
        float xv = xcol[wave*16 + (g16 << 2) + r];
        float hv = T2[n][r] + b2c;
        float gv = sigmoid_f(Gg[n][r] + bgc);
        T2[n][r] = fmaf(xv, wkc, bkc) + hv*gv;
      }
    }
    #pragma unroll
    for (int r = 0; r < 4; ++r){
      float s = 0.f;
      #pragma unroll
      for (int n = 0; n < 8; ++n) s += T2[n][r];
      #pragma unroll
      for (int m = 1; m < 16; m <<= 1) s += __shfl_xor(s, m, 64);
      float mu = s * (1.0f/128.0f);
      float vs = 0.f;
      #pragma unroll
      for (int n = 0; n < 8; ++n){ float d = T2[n][r]-mu; vs += d*d; }
      #pragma unroll
      for (int m = 1; m < 16; m <<= 1) vs += __shfl_xor(vs, m, 64);
      float rstd = rsqrtf(vs * (1.0f/128.0f) + 1e-5f);
      #pragma unroll
      for (int n = 0; n < 8; ++n){
        int c = n*16 + l16;
        T2[n][r] = (T2[n][r]-mu)*rstd*vecs[6*128+c] + vecs[7*128+c];
      }
    }
    #pragma unroll
    for (int n = 0; n < 8; ++n)
      #pragma unroll
      for (int r = 0; r < 4; ++r)
        Ht[(wave*16 + (g16<<2) + r)*132 + n*16 + l16] = T2[n][r];

    // ---- phase 2: acc1 += proc@cfc1w[f]; accS += proc@cskw[f] ----
    for (int kc = 0; kc < 4; ++kc){
      __syncthreads();
      stagePair(hiP, loP, 18+f, 27+f, kc, Bs, tid);
      bf16x8 aH, aL;
      {
        const float* hp = &Ht[arow*132 + kc*32 + (g16 << 3)];
        float4 v0 = *(const float4*)hp;
        float4 v1 = *(const float4*)(hp + 4);
        #pragma unroll
        for (int j = 0; j < 8; ++j){
          float v = (j < 4) ? comp4(v0, j) : comp4(v1, j-4);
          short sh, sl; split2(v, sh, sl);
          aH[j] = sh; aL[j] = sl;
        }
      }
      __syncthreads();
      gemm3(Bs,        aH, aL, acc1, lane);
      gemm3(Bs + 8192, aH, aL, accS, lane);
    }
  }

  // ---- fused comb-GRN tail ----
  #pragma unroll
  for (int n = 0; n < 8; ++n){
    int c = n*16 + l16;
    float b1c = cfc1b[c], skc = cskb[c];
    #pragma unroll
    for (int r = 0; r < 4; ++r){
      Ht[(wave*16 + (g16<<2) + r)*132 + c] = elu_f(acc1[n][r] + b1c);
      accS[n][r] += skc;
    }
  }
  f32x4 T2[8], Gg[8];
  #pragma unroll
  for (int n = 0; n < 8; ++n){ T2[n] = z4; Gg[n] = z4; }

  for (int kc = 0; kc < 4; ++kc){
    __syncthreads();
    stagePair(hiP, loP, 36, 37, kc, Bs, tid);
    bf16x8 aH, aL;
    {
      const float* hp = &Ht[arow*132 + kc*32 + (g16 << 3)];
      float4 v0 = *(const float4*)hp;
      float4 v1 = *(const float4*)(hp + 4);
      #pragma unroll
      for (int j = 0; j < 8; ++j){
        float v = (j < 4) ? comp4(v0, j) : comp4(v1, j-4);
        short sh, sl; split2(v, sh, sl);
        aH[j] = sh; aL[j] = sl;
      }
    }
    __syncthreads();
    gemm3(Bs,        aH, aL, T2, lane);
    gemm3(Bs + 8192, aH, aL, Gg, lane);
  }

  #pragma unroll
  for (int n = 0; n < 8; ++n){
    int c = n*16 + l16;
    float f2b = cfc2b[c], gbb = cgb[c];
    #pragma unroll
    for (int r = 0; r < 4; ++r){
      float hv = (T2[n][r] + f2b) * sigmoid_f(Gg[n][r] + gbb);
      T2[n][r] = accS[n][r] + hv;
    }
  }
  #pragma unroll
  for (int r = 0; r < 4; ++r){
    float s = 0.f;
    #pragma unroll
    for (int n = 0; n < 8; ++n) s += T2[n][r];
    #pragma unroll
    for (int m = 1; m < 16; m <<= 1) s += __shfl_xor(s, m, 64);
    float mu = s * (1.0f/128.0f);
    float vs = 0.f;
    #pragma unroll
    for (int n = 0; n < 8; ++n){ float d = T2[n][r]-mu; vs += d*d; }
    #pragma unroll
    for (int m = 1; m < 16; m <<= 1) vs += __shfl_xor(vs, m, 64);
    float rstd = rsqrtf(vs * (1.0f/128.0f) + 1e-5f);
    long rr = row0 + wave*16 + (g16<<2) + r;
    #pragma unroll
    for (int n = 0; n < 8; ++n){
      int c = n*16 + l16;
      outp[rr*128 + c] = (T2[n][r]-mu)*rstd*clns[c] + clnb[c];
    }
  }
}

// ---------------------------------------------------------------------------
// fp32 GEMM microkernel (grn_core only)
// ---------------------------------------------------------------------------
DI void gemm_tile_2(const float* Ht, const float* WtA, const float* WtB,
                    float accA[4][8], float accB[4][8], int tr, int tc, int kt)
{
  #pragma unroll
  for (int k4 = 0; k4 < 8; ++k4){
    float4 a4[4];
    #pragma unroll
    for (int i = 0; i < 4; ++i)
      a4[i] = *(const float4*)&Ht[(tr*4+i)*132 + kt*32 + k4*4];
    #pragma unroll
    for (int u = 0; u < 4; ++u){
      float4 bAlo = *(const float4*)&WtA[(k4*4+u)*132 + tc*8];
      float4 bAhi = *(const float4*)&WtA[(k4*4+u)*132 + tc*8 + 4];
      float4 bBlo = *(const float4*)&WtB[(k4*4+u)*132 + tc*8];
      float4 bBhi = *(const float4*)&WtB[(k4*4+u)*132 + tc*8 + 4];
      #pragma unroll
      for (int i = 0; i < 4; ++i){
        float av = comp4(a4[i], u);
        #pragma unroll
        for (int j = 0; j < 8; ++j){
          float bA = (j < 4) ? comp4(bAlo, j) : comp4(bAhi, j-4);
          float bB = (j < 4) ? comp4(bBlo, j) : comp4(bBhi, j-4);
          accA[i][j] = fmaf(av, bA, accA[i][j]);
          accB[i][j] = fmaf(av, bB, accB[i][j]);
        }
      }
    }
  }
}

// ---------------------------------------------------------------------------
// Kernel 2: GRN core (post-GRN, M=12288)
// ---------------------------------------------------------------------------
__global__ __launch_bounds__(256, 2) void grn_core_kernel(
    const float* __restrict__ Z1, const float* __restrict__ S,
    const float* __restrict__ fc2w, const float* __restrict__ fc2b,
    const float* __restrict__ gw,   const float* __restrict__ gb,
    const float* __restrict__ lns,  const float* __restrict__ lnb,
    float* __restrict__ outp, int M)
{
  __shared__ float Ht[64*132];
  __shared__ float WtA[32*132];
  __shared__ float WtB[32*132];

  const int tid = threadIdx.x;
  const int tr = tid >> 4, tc = tid & 15;
  const int row0 = blockIdx.x * 64;

  #pragma unroll
  for (int i = 0; i < 8; ++i){
    int fi = tid + i*256;
    int row = fi >> 5, c4 = (fi & 31)*4;
    long r = row0 + row;
    float4 z = make_float4(0.f,0.f,0.f,0.f);
    if (r < M) z = *(const float4*)&Z1[r*128 + c4];
    z.x = elu_f(z.x); z.y = elu_f(z.y); z.z = elu_f(z.z); z.w = elu_f(z.w);
    *(float4*)&Ht[row*132 + c4] = z;
  }

  float T2[4][8], Gg[4][8];
  #pragma unroll
  for (int i = 0; i < 4; ++i)
    #pragma unroll
    for (int j = 0; j < 8; ++j){ T2[i][j] = 0.f; Gg[i][j] = 0.f; }

  for (int kt = 0; kt < 4; ++kt){
    __syncthreads();
    #pragma unroll
    for (int i = 0; i < 4; ++i){
      int li = tid + i*256;
      int kk = li >> 5, c4 = (li & 31)*4;
      *(float4*)&WtA[kk*132 + c4] = *(const float4*)&fc2w[(kt*32+kk)*128 + c4];
      *(float4*)&WtB[kk*132 + c4] = *(const float4*)&gw  [(kt*32+kk)*128 + c4];
    }
    __syncthreads();
    gemm_tile_2(Ht, WtA, WtB, T2, Gg, tr, tc, kt);
  }

  float val[4][8];
  #pragma unroll
  for (int i = 0; i < 4; ++i){
    long r = row0 + tr*4 + i;
    float4 s0 = make_float4(0,0,0,0), s1 = make_float4(0,0,0,0);
    if (r < M){
      s0 = *(const float4*)&S[r*128 + tc*8];
      s1 = *(const float4*)&S[r*128 + tc*8 + 4];
    }
    #pragma unroll
    for (int j = 0; j < 8; ++j){
      int c = tc*8 + j;
      float sv = (j < 4) ? comp4(s0, j) : comp4(s1, j-4);
      float hv = (T2[i][j] + fc2b[c]) * sigmoid_f(Gg[i][j] + gb[c]);
      val[i][j] = sv + hv;
    }
  }
  #pragma unroll
  for (int i = 0; i < 4; ++i){
    float s = 0.f;
    #pragma unroll
    for (int j = 0; j < 8; ++j) s += val[i][j];
    #pragma unroll
    for (int m = 1; m < 16; m <<= 1) s += __shfl_xor(s, m, 64);
    float mu = s * (1.0f/128.0f);
    float vs = 0.f;
    #pragma unroll
    for (int j = 0; j < 8; ++j){ float d = val[i][j]-mu; vs += d*d; }
    #pragma unroll
    for (int m = 1; m < 16; m <<= 1) vs += __shfl_xor(vs, m, 64);
    float rstd = rsqrtf(vs * (1.0f/128.0f) + 1e-5f);
    long r = row0 + tr*4 + i;
    if (r < M){
      #pragma unroll
      for (int j = 0; j < 8; ++j){
        int c = tc*8 + j;
        outp[r*128 + c] = (val[i][j]-mu)*rstd*lns[c] + lnb[c];
      }
    }
  }
}

// ---------------------------------------------------------------------------
// Kernel 4: LSTM recurrence (batch-parallel, Whh in VGPRs, readlane broadcast)
// ---------------------------------------------------------------------------
__global__ __launch_bounds__(512, 2) void lstm_rec_kernel(
    const float* __restrict__ gx, int nsteps, int gbs, int gts,
    const float* __restrict__ Whh,
    float* __restrict__ h_state, float* __restrict__ c_state, int init_zero,
    float* __restrict__ seq_out, long seq_b_stride)
{
  __shared__ float hbuf[2][128];
  __shared__ float act[4][2][128];

  const int tid = threadIdx.x;
  const int lane = tid & 63;
  const int b0 = blockIdx.x * 2;
  const int type = tid >> 7;
  const int u = tid & 127;

  float4 w[32];
  #pragma unroll
  for (int i = 0; i < 32; ++i)
    w[i] = *(const float4*)&Whh[(long)tid*128 + i*4];

  if (tid < 256){
    int bi = tid >> 7, uu = tid & 127;
    hbuf[bi][uu] = init_zero ? 0.f : h_state[(long)(b0+bi)*128 + uu];
  }
  float creg0 = 0.f, creg1 = 0.f;
  if (tid < 128 && !init_zero){
    creg0 = c_state[(long)b0*128 + tid];
    creg1 = c_state[(long)(b0+1)*128 + tid];
  }

  for (int t = 0; t < nsteps; ++t){
    __syncthreads();
    float hA0 = hbuf[0][lane],    hA1 = hbuf[0][64+lane];
    float hB0 = hbuf[1][lane],    hB1 = hbuf[1][64+lane];
    float acc0  = gx[(long)b0*gbs     + (long)t*gts + tid];
    float acc1  = gx[(long)(b0+1)*gbs + (long)t*gts + tid];
    float acc0b = 0.f, acc1b = 0.f;
    #pragma unroll
    for (int j = 0; j < 64; ++j){
      float wv = comp4(w[j>>2], j&3);
      float s0 = __int_as_float(__builtin_amdgcn_readlane(__float_as_int(hA0), j));
      float s1 = __int_as_float(__builtin_amdgcn_readlane(__float_as_int(hB0), j));
      acc0 = fmaf(wv, s0, acc0);
      acc1 = fmaf(wv, s1, acc1);
    }
    #pragma unroll
    for (int j = 0; j < 64; ++j){
      float wv = comp4(w[16 + (j>>2)], j&3);
      float s0 = __int_as_float(__builtin_amdgcn_readlane(__float_as_int(hA1), j));
      float s1 = __int_as_float(__builtin_amdgcn_readlane(__float_as_int(hB1), j));
      acc0b = fmaf(wv, s0, acc0b);
      acc1b = fmaf(wv, s1, acc1b);
    }
    acc0 += acc0b; acc1 += acc1b;

    float a0, a1;
    if (type == 2){ a0 = tanh_f(acc0); a1 = tanh_f(acc1); }
    else          { a0 = sigmoid_f(acc0); a1 = sigmoid_f(acc1); }
    act[type][0][u] = a0;
    act[type][1][u] = a1;
    __syncthreads();
    if (tid < 128){
      float cn0 = act[1][0][u]*creg0 + act[0][0][u]*act[2][0][u];
      float hn0 = act[3][0][u]*tanh_f(cn0);
      creg0 = cn0;
      float cn1 = act[1][1][u]*creg1 + act[0][1][u]*act[2][1][u];
      float hn1 = act[3][1][u]*tanh_f(cn1);
      creg1 = cn1;
      hbuf[0][u] = hn0;
      hbuf[1][u] = hn1;
      seq_out[(long)b0*seq_b_stride     + (long)t*128 + u] = hn0;
      seq_out[(long)(b0+1)*seq_b_stride + (long)t*128 + u] = hn1;
    }
  }
  __syncthreads();
  if (tid < 256){
    int bi = tid >> 7, uu = tid & 127;
    h_state[(long)(b0+bi)*128 + uu] = hbuf[bi][uu];
  }
  if (tid < 128){
    c_state[(long)b0*128 + tid]     = creg0;
    c_state[(long)(b0+1)*128 + tid] = creg1;
  }
}

// ---------------------------------------------------------------------------
// Kernel 5: attention core per (batch, head)
// ---------------------------------------------------------------------------
__global__ __launch_bounds__(256) void attn_kernel(
    const float* __restrict__ q, const float* __restrict__ k,
    const float* __restrict__ v, float* __restrict__ ctx)
{
  __shared__ float kb[168*33];
  __shared__ float vbuf[168*33];
  __shared__ float qb[24*33];
  __shared__ float sc[24*172];

  const int tid = threadIdx.x;
  const int bh = blockIdx.x;
  const int b = bh >> 2, h = bh & 3;

  for (int l = tid; l < 1344; l += 256){
    int t = l >> 3, d4 = (l & 7)*4;
    float4 kv = *(const float4*)&k[((long)(b*168 + t))*128 + h*32 + d4];
    kb[t*33+d4+0] = kv.x; kb[t*33+d4+1] = kv.y; kb[t*33+d4+2] = kv.z; kb[t*33+d4+3] = kv.w;
    float4 vv = *(const float4*)&v[((long)(b*168 + t))*128 + h*32 + d4];
    vbuf[t*33+d4+0] = vv.x; vbuf[t*33+d4+1] = vv.y; vbuf[t*33+d4+2] = vv.z; vbuf[t*33+d4+3] = vv.w;
  }
  if (tid < 192){
    int t = tid >> 3, d4 = (tid & 7)*4;
    float4 qv = *(const float4*)&q[((long)(b*24 + t))*128 + h*32 + d4];
    qb[t*33+d4+0] = qv.x; qb[t*33+d4+1] = qv.y; qb[t*33+d4+2] = qv.z; qb[t*33+d4+3] = qv.w;
  }
  __syncthreads();

  if (tid < 168){
    int j = tid;
    for (int i = 0; i < 24; ++i){
      float s = 0.f;
      #pragma unroll
      for (int d = 0; d < 32; ++d)
        s = fmaf(qb[i*33+d], kb[j*33+d], s);
      sc[i*172 + j] = s * 0.17677669529663687f;
    }
  }
  __syncthreads();

  const int lane = tid & 63;
  const int wv = tid >> 6;
  for (int m = 0; m < 6; ++m){
    int i = wv + 4*m;
    float v0 = sc[i*172 + lane];
    float v1 = sc[i*172 + 64 + lane];
    float v2 = (lane < 40) ? sc[i*172 + 128 + lane] : -1e30f;
    float mx = fmaxf(v0, fmaxf(v1, v2));
    #pragma unroll
    for (int s = 1; s < 64; s <<= 1) mx = fmaxf(mx, __shfl_xor(mx, s, 64));
    float e0 = __expf(v0 - mx), e1 = __expf(v1 - mx);
    float e2 = (lane < 40) ? __expf(v2 - mx) : 0.f;
    float sm = e0 + e1 + e2;
    #pragma unroll
    for (int s = 1; s < 64; s <<= 1) sm += __shfl_xor(sm, s, 64);
    float inv = 1.0f / sm;
    sc[i*172 + lane]      = e0*inv;
    sc[i*172 + 64 + lane] = e1*inv;
    if (lane < 40) sc[i*172 + 128 + lane] = e2*inv;
  }
  __syncthreads();

  #pragma unroll
  for (int kk = 0; kk < 3; ++kk){
    int o = tid + kk*256;
    int i = o >> 5, d = o & 31;
    float s = 0.f;
    for (int j = 0; j < 168; ++j)
      s = fmaf(sc[i*172 + j], vbuf[j*33 + d], s);
    ctx[((long)(b*24 + i))*128 + h*32 + d] = s;
  }
}

// ---------------------------------------------------------------------------
// Kernel 6: final projection (12288,128)->(12288,6)
// ---------------------------------------------------------------------------
__global__ void fcout_kernel(const float* __restrict__ post,
                             const float* __restrict__ w,
                             const float* __restrict__ bias,
                             float* __restrict__ out)
{
  int gid = blockIdx.x*256 + threadIdx.x;
  if (gid >= 12288*OUT_) return;
  int r = gid / OUT_, o = gid - r*OUT_;
  float s = bias[o];
  #pragma unroll 8
  for (int kk = 0; kk < 128; ++kk)
    s = fmaf(post[(long)r*128 + kk], w[kk*OUT_ + o], s);
  out[gid] = s;
}

// Kernel 7: bias sums
__global__ void biasprep_kernel(const float* __restrict__ ebih, const float* __restrict__ ebhh,
                                const float* __restrict__ dbih, const float* __restrict__ dbhh,
                                float* __restrict__ outb)
{
  int i = blockIdx.x*256 + threadIdx.x;
  if (i < 1024)       outb[i] = ebih[i] + ebhh[i];
  else if (i < 2048)  outb[i] = dbih[i-1024] + dbhh[i-1024];
}

// ---------------------------------------------------------------------------
extern "C" void kernel_launch(void* const* d_in, const int* in_sizes, int n_in,
                              void* d_out, int out_size, void* d_ws, size_t ws_size,
                              hipStream_t stream)
{
  const float* x_g   = (const float*)d_in[0];
  const float* vfc1w = (const float*)d_in[1];
  const float* vfc1b = (const float*)d_in[2];
  const float* vfc2w = (const float*)d_in[3];
  const float* vfc2b = (const float*)d_in[4];
  const float* vgw   = (const float*)d_in[5];
  const float* vgb   = (const float*)d_in[6];
  const float* vskw  = (const float*)d_in[7];
  const float* vskb  = (const float*)d_in[8];
  const float* vlns  = (const float*)d_in[9];
  const float* vlnb  = (const float*)d_in[10];
  const float* cfc1w = (const float*)d_in[11];
  const float* cfc1b = (const float*)d_in[12];
  const float* cfc2w = (const float*)d_in[13];
  const float* cfc2b = (const float*)d_in[14];
  const float* cgw   = (const float*)d_in[15];
  const float* cgb   = (const float*)d_in[16];
  const float* cskw  = (const float*)d_in[17];
  const float* cskb  = (const float*)d_in[18];
  const float* clns  = (const float*)d_in[19];
  const float* clnb  = (const float*)d_in[20];
  const float* eWih  = (const float*)d_in[21];
  const float* eWhh  = (const float*)d_in[22];
  const float* ebih  = (const float*)d_in[23];
  const float* ebhh  = (const float*)d_in[24];
  const float* dWih  = (const float*)d_in[25];
  const float* dWhh  = (const float*)d_in[26];
  const float* dbih  = (const float*)d_in[27];
  const float* dbhh  = (const float*)d_in[28];
  const float* qkvw  = (const float*)d_in[29];
  const float* qkvb  = (const float*)d_in[30];
  const float* aow   = (const float*)d_in[31];
  const float* aob   = (const float*)d_in[32];
  const float* pfc1w = (const float*)d_in[33];
  const float* pfc1b = (const float*)d_in[34];
  const float* pfc2w = (const float*)d_in[35];
  const float* pfc2b = (const float*)d_in[36];
  const float* pgw   = (const float*)d_in[37];
  const float* pgb   = (const float*)d_in[38];
  const float* plns  = (const float*)d_in[39];
  const float* plnb  = (const float*)d_in[40];
  const float* fcw   = (const float*)d_in[41];
  const float* fcb   = (const float*)d_in[42];

  float* ws = (float*)d_ws;
  // layout: R1(11,010,048) R2(11,010,048) Dd(23,592,960) st(264,192) pk2(344,064)
  float* R1 = ws;
  float* R2 = ws + 11010048;
  float* Dd = ws + 22020096;
  float* st = ws + 45613056;

  float* combined = R1;
  float* enc_out  = R1;
  float* seq1     = R2;
  float* dseq1    = R2;
  float* dec_out  = R2 + 1572864;
  float* ctxb     = R2 + 3145728;
  float* attn_o   = R2 + 4718592;
  float* z1p      = R2 + 6291456;
  float* postb    = R2 + 7864320;
  float* gxb      = Dd;
  float* qb       = Dd;
  float* kb       = Dd + 1572864;
  float* vb       = Dd + 12582912;
  float* h0s = st, *c0s = st + 65536, *h1s = st + 131072, *c1s = st + 196608;
  float* biasb = st + 262144;           // 2048 floats

  // vsn packed planes: alias Dd head (dead before gxb first written)
  unsigned short* hiP = (unsigned short*)Dd;
  unsigned short* loP = hiP + 622592;

  // pipeline packed planes: persistent, after st
  unsigned short* hiP2 = (unsigned short*)(st + 264192);
  unsigned short* loP2 = hiP2 + 344064;   // ends at ws + 46,221,312 floats

  biasprep_kernel<<<8, 256, 0, stream>>>(ebih, ebhh, dbih, dbhh, biasb);
  pack_kernel<<<2432, 256, 0, stream>>>(vfc2w, vgw, cfc1w, cskw, cfc2w, cgw,
                                        hiP, loP);
  pack2_kernel<<<1344, 256, 0, stream>>>(eWih, dWih, qkvw, aow, pfc1w,
                                         hiP2, loP2);

  vsn_comb_mfma<<<1344, 256, 0, stream>>>(x_g, vfc1w, vfc1b, vfc2b, vgb,
                                          vskw, vskb, vlns, vlnb,
                                          cfc1b, cskb, cfc2b, cgb, clns, clnb,
                                          hiP, loP, combined);

  // encoder: 2 layers x 3 time-chunks of 56
  for (int l = 0; l < 2; ++l){
    const float* Whh = eWhh + l*65536;
    const float* src = (l == 0) ? combined : seq1;
    float* dst = (l == 0) ? seq1 : enc_out;
    float* hs  = (l == 0) ? h0s : h1s;
    float* cs  = (l == 0) ? c0s : c1s;
    for (int c = 0; c < 3; ++c){
      int t0 = c*CHUNK;
      mfma_gemm<<<dim3(448,4), 256, 0, stream>>>(src + (long)t0*128,
          hiP2, loP2, l*4, biasb + l*512, gxb,
          B_*CHUNK, 512, CHUNK, (long)TE*128, 128);
      lstm_rec_kernel<<<256, 512, 0, stream>>>(gxb, CHUNK, CHUNK*512, 512, Whh,
          hs, cs, (c == 0) ? 1 : 0, dst + (long)t0*128, (long)TE*128);
    }
  }

  // decoder layer 1: input = enc_out[:,167,:] repeated
  mfma_gemm<<<dim3(8,4), 256, 0, stream>>>(enc_out + (long)167*128,
      hiP2, loP2, 8, biasb + 1024, gxb,
      B_, 512, 1, (long)TE*128, 128);
  lstm_rec_kernel<<<256, 512, 0, stream>>>(gxb, TDD, 512, 0, dWhh,
      h0s, c0s, 0, dseq1, (long)TDD*128);

  // decoder layer 2
  mfma_gemm<<<dim3(192,4), 256, 0, stream>>>(dseq1,
      hiP2, loP2, 12, biasb + 1536, gxb,
      B_*TDD, 512, B_*TDD, 0, 128);
  lstm_rec_kernel<<<256, 512, 0, stream>>>(gxb, TDD, TDD*512, 512, dWhh + 65536,
      h1s, c1s, 0, dec_out, (long)TDD*128);

  // attention projections
  mfma_gemm<<<dim3(192,1),  256, 0, stream>>>(dec_out, hiP2, loP2, 16,
      qkvb,     qb, B_*TDD, 128, B_*TDD, 0, 128);
  mfma_gemm<<<dim3(1344,1), 256, 0, stream>>>(enc_out, hiP2, loP2, 17,
      qkvb+128, kb, B_*TE,  128, B_*TE,  0, 128);
  mfma_gemm<<<dim3(1344,1), 256, 0, stream>>>(enc_out, hiP2, loP2, 18,
      qkvb+256, vb, B_*TE,  128, B_*TE,  0, 128);

  attn_kernel<<<2048, 256, 0, stream>>>(qb, kb, vb, ctxb);

  mfma_gemm<<<dim3(192,1), 256, 0, stream>>>(ctxb,   hiP2, loP2, 19,
      aob,   attn_o, B_*TDD, 128, B_*TDD, 0, 128);
  mfma_gemm<<<dim3(192,1), 256, 0, stream>>>(attn_o, hiP2, loP2, 20,
      pfc1b, z1p,    B_*TDD, 128, B_*TDD, 0, 128);

  grn_core_kernel<<<192, 256, 0, stream>>>(z1p, attn_o, pfc2w, pfc2b, pgw, pgb,
                                           plns, plnb, postb, B_*TDD);

  fcout_kernel<<<288, 256, 0, stream>>>(postb, fcw, fcb, (float*)d_out);
}